// Round 1
// baseline (273.523 us; speedup 1.0000x reference)
//
#include <hip/hip_runtime.h>
#include <hip/hip_bf16.h>

// Problem constants
#define B_  2
#define L_  512
#define D_  768
#define H_  12
#define E_  32
#define M_  4
#define P_  256
#define EMB_ 768
#define BS_ 64
#define C_  97
#define N_  (B_*P_)   // 512

#define KTOT_    49152      // EMB*BS
#define CPAD_    112        // 97 padded to 7*16
#define KSPLIT_  64
#define KCHUNK_  (KTOT_/KSPLIT_)   // 768, 12 ks-steps of 64

typedef __hip_bfloat16 bf16;
typedef __attribute__((ext_vector_type(8))) short bf16x8;
typedef __attribute__((ext_vector_type(4))) float f32x4;

__device__ inline float ldIn(const void* p, long idx, int isbf) {
    return isbf ? (float)((const bf16*)p)[idx] : ((const float*)p)[idx];
}

__device__ inline unsigned short f2bf(float f) {
    bf16 h = (bf16)f;
    return *(unsigned short*)&h;
}

__device__ inline float bf2f(unsigned short u) {
    bf16 h = *(bf16*)&u;
    return (float)h;
}

// ---------------- K0: dtype detection + c23 zero-init ----------------
__global__ void dtype_detect(const void* __restrict__ seq, int* __restrict__ flag,
                             float* __restrict__ c23) {
    __shared__ int cnt;
    if (threadIdx.x == 0) cnt = 0;
    if (threadIdx.x < 2*C_) c23[threadIdx.x] = 0.f;
    __syncthreads();
    const unsigned short* u = (const unsigned short*)seq;
    int bad = 0;
    for (int i = threadIdx.x; i < 1024; i += 256) {
        unsigned short e = (u[i] >> 7) & 0xFF;
        if (e >= 140) bad++;
    }
    atomicAdd(&cnt, bad);
    __syncthreads();
    if (threadIdx.x == 0) flag[0] = (cnt < 16) ? 1 : 0;   // 1 = bf16 inputs
}

// ---------------- prep: z<8 transposes (32k x 64n), z=8 W_bil->f32, z=9 c23, z=10 W_rel conv ----
struct PrepArgs {
    const void* src[8];
    long off[8];
    int K[8];
    int Ncols[8];
    int Npad[8];
    unsigned short* dst[8];
    const void* W_bil;  float* W_bilF;
    const void* b_f; const void* W_unet; const void* b_unet;
    const void* W_mlp; const void* b_mlp; float* c23;
    const void* W_rel; unsigned short* WBt;
};

union PrepSm {
    float T[32][65];                 // 8320 B
    unsigned short TW[CPAD_][72];    // 16128 B
};

__global__ void prep_kernel(PrepArgs a, const int* __restrict__ dtf) {
    int isbf = dtf[0];
    int z = blockIdx.z;
    __shared__ PrepSm sm;
    int tid = threadIdx.x;
    if (z < 8) {
        int K = a.K[z], Ncols = a.Ncols[z], Npad = a.Npad[z];
        int k0 = blockIdx.x*32, n0 = blockIdx.y*64;
        if (k0 >= K || n0 >= Npad) return;
        const void* src = a.src[z];
        long off = a.off[z];
        unsigned short* dst = a.dst[z];
        // read: 64 consecutive cols per row (coalesced 128/256 B)
        int c64 = tid & 63, r4 = tid >> 6;
        for (int p = 0; p < 8; p++) {
            int r = r4 + p*4;
            int n = n0 + c64;
            sm.T[r][c64] = (n < Ncols) ? ldIn(src, off + (long)(k0+r)*Ncols + n, isbf) : 0.f;
        }
        __syncthreads();
        // write: 32 consecutive k per n (coalesced)
        int cc = tid & 31, n8 = tid >> 5;
        for (int p = 0; p < 8; p++) {
            int nn = n8 + p*8;
            dst[(long)(n0+nn)*K + k0 + cc] = f2bf(sm.T[cc][nn]);
        }
    } else if (z == 8) {
        int lin = blockIdx.y*48 + blockIdx.x;
        int idx = lin*256 + tid;
        if (idx < 291*C_) a.W_bilF[idx] = ldIn(a.W_bil, idx, isbf);
    } else if (z == 9) {
        // c23 partial: 8 blocks x 96 d-rows, coalesced over c, atomic accumulate
        int lin = blockIdx.y*48 + blockIdx.x;
        if (lin >= 8) return;
        int c = tid;
        if (c >= C_) return;
        float s2 = 0.f, s3 = 0.f;
        int d0 = lin*96;
        for (int i = 0; i < 96; i++) {
            int d = d0 + i;
            float bf = ldIn(a.b_f, d, isbf);
            s2 += bf * ldIn(a.W_unet, (long)d*C_ + c, isbf);
            s3 += bf * ldIn(a.W_mlp,  (long)d*C_ + c, isbf);
        }
        if (lin == 0) {
            s2 += ldIn(a.b_unet, c, isbf);
            s3 += ldIn(a.b_mlp,  c, isbf);
        }
        atomicAdd(&a.c23[c], s2);
        atomicAdd(&a.c23[C_ + c], s3);
    } else {
        // W_rel -> WBt[c][k] bf16, c padded to 112; 64-k tiles
        int lin = blockIdx.y*48 + blockIdx.x;
        if (lin >= KTOT_/64) return;
        int k0 = lin * 64;
        for (int idx = tid; idx < 64*97; idx += 256) {
            int kk = idx / 97, c = idx % 97;
            sm.TW[c][kk] = f2bf(ldIn(a.W_rel, (long)(k0+kk)*C_ + c, isbf));
        }
        for (int idx = tid; idx < 15*64; idx += 256) {
            sm.TW[97 + (idx>>6)][idx & 63] = 0;
        }
        __syncthreads();
        for (int t = 0; t < 4; t++) {
            int idx = tid + t*256;      // < 896 = 112*8
            if (idx < 896) {
                int c = idx >> 3, kc = idx & 7;
                *(uint4*)(a.WBt + (long)c*KTOT_ + k0 + kc*8) = *(uint4*)&sm.TW[c][kc*8];
            }
        }
    }
}

// ---------------- gather: bx<768 entatt, else ment ----------------
__global__ void gather_kernel(const void* __restrict__ seq, const void* __restrict__ attn,
                              const int* __restrict__ entity_pos,
                              unsigned short* __restrict__ mentb, float* __restrict__ ent_emb,
                              float* __restrict__ ent_att, const int* __restrict__ dtf) {
    int isbf = dtf[0];
    if (blockIdx.x < 768) {
        int beh = blockIdx.x;
        int h = beh % H_;
        int be = beh / H_;
        int b = be >> 5;
        int pos[M_];
        for (int m = 0; m < M_; m++) pos[m] = entity_pos[be*M_+m] + 1;
        for (int l = threadIdx.x; l < L_; l += 256) {
            float s = 0.f;
            for (int m = 0; m < M_; m++)
                s += ldIn(attn, (((long)(b*H_ + h))*L_ + pos[m])*L_ + l, isbf);
            ent_att[(long)beh*L_ + l] = 0.25f * s;
        }
    } else {
        int be = blockIdx.x - 768;     // 0..63
        int b = be >> 5;
        int pos[M_];
        for (int m = 0; m < M_; m++) pos[m] = entity_pos[be*M_+m] + 1;
        for (int d = threadIdx.x; d < D_; d += 256) {
            float x[M_];
            for (int m = 0; m < M_; m++) {
                x[m] = ldIn(seq, ((long)b*L_ + pos[m])*D_ + d, isbf);
                mentb[((long)be*M_ + m)*D_ + d] = f2bf(x[m]);
            }
            float mx = fmaxf(fmaxf(x[0],x[1]), fmaxf(x[2],x[3]));
            float s = expf(x[0]-mx)+expf(x[1]-mx)+expf(x[2]-mx)+expf(x[3]-mx);
            ent_emb[(long)be*D_ + d] = mx + logf(s);
        }
    }
}

// ---------------- K3: ht_att (bf16) = normalize_L( mean_H(ha*ta) ) ----------------
__global__ void htatt_kernel(const float* __restrict__ ent_att, const int* __restrict__ hts,
                             unsigned short* __restrict__ htb) {
    int bp = blockIdx.x;            // 512 blocks
    int b = bp >> 8;
    int h_e = hts[bp*2+0], t_e = hts[bp*2+1];
    const float* ea_h = ent_att + (long)((b*E_ + h_e)*H_)*L_;
    const float* ea_t = ent_att + (long)((b*E_ + t_e)*H_)*L_;
    __shared__ float red[256];
    float v[2];
    for (int t = 0; t < 2; t++) {
        int l = threadIdx.x + t*256;
        float s = 0.f;
        for (int h = 0; h < H_; h++) s += ea_h[h*L_+l] * ea_t[h*L_+l];
        v[t] = s * (1.0f/H_);
    }
    red[threadIdx.x] = v[0] + v[1];
    __syncthreads();
    for (int off = 128; off > 0; off >>= 1) {
        if (threadIdx.x < off) red[threadIdx.x] += red[threadIdx.x+off];
        __syncthreads();
    }
    float inv = 1.0f / (red[0] + 1e-5f);
    for (int t = 0; t < 2; t++) {
        int l = threadIdx.x + t*256;
        htb[(long)bp*L_ + l] = f2bf(v[t] * inv);
    }
}

// ---------------- catb: hcatb=[hs,rs], tcatb=[ts,rs] in bf16 ----------------
__global__ void catb_kernel(const float* __restrict__ ent_emb, const float* __restrict__ rs,
                            const int* __restrict__ hts,
                            unsigned short* __restrict__ hcatb, unsigned short* __restrict__ tcatb) {
    int n = blockIdx.x;             // 512
    int b = n >> 8;
    int h_e = hts[n*2+0], t_e = hts[n*2+1];
    const float* eh = ent_emb + (long)(b*E_ + h_e)*D_;
    const float* et = ent_emb + (long)(b*E_ + t_e)*D_;
    const float* r  = rs + (long)n*D_;
    for (int k = threadIdx.x; k < D_; k += 256) {
        hcatb[(long)n*1536 + k] = f2bf(eh[k]);
        tcatb[(long)n*1536 + k] = f2bf(et[k]);
        unsigned short rb = f2bf(r[k]);
        hcatb[(long)n*1536 + 768 + k] = rb;
        tcatb[(long)n*1536 + 768 + k] = rb;
    }
}

// ---------------- Generic MFMA GEMM (double-buffered), 32x32 tiles ----------------
// Tile shrunk from 64x64 to 32x32: grids grow 4x (192->768 blocks for gemmA/B),
// LDS 36.9KB->18.4KB. These launches were latency-bound at <1 block/CU.
struct MfmaJob {
    const unsigned short* A[4];
    const unsigned short* Bt[4];
    const void* bias[4];
    void* C[4];
    int K[4];
    int ldc[4];
    int act[4];
    int obf[4];
};

__global__ void mfma_nt2_kernel(MfmaJob args, const int* __restrict__ dtf) {
    int z = blockIdx.z;
    const unsigned short* A  = args.A[z];
    const unsigned short* Bt = args.Bt[z];
    const void* bias = args.bias[z];
    void* C = args.C[z];
    int K = args.K[z], ldc = args.ldc[z], act = args.act[z], obf = args.obf[z];
    __shared__ unsigned short Al[2][32][72];
    __shared__ unsigned short Btl[2][32][72];
    int m0 = blockIdx.x*32, n0 = blockIdx.y*32;
    int tid = threadIdx.x, wave = tid>>6, lane = tid&63;
    int lm = lane&15, lq = lane>>4;
    int rowg = wave>>1, cgrp = wave&1;   // wave -> (row half, col half)
    int rr = tid >> 3;                // 0..31
    int kc = (tid & 7) * 8;           // col offset in ushorts
    uint4 ra, rb;

    ra = *(const uint4*)(A  + (long)(m0+rr)*K + kc);
    rb = *(const uint4*)(Bt + (long)(n0+rr)*K + kc);
    *(uint4*)&Al[0][rr][kc]  = ra;
    *(uint4*)&Btl[0][rr][kc] = rb;

    int nst = K >> 6;
    f32x4 acc = {};
    for (int ks = 0; ks < nst; ks++) {
        __syncthreads();
        if (ks+1 < nst) {
            int k0 = (ks+1) << 6;
            ra = *(const uint4*)(A  + (long)(m0+rr)*K + k0 + kc);
            rb = *(const uint4*)(Bt + (long)(n0+rr)*K + k0 + kc);
        }
        int cb = ks & 1;
        #pragma unroll
        for (int half = 0; half < 2; half++) {
            bf16x8 af  = *(bf16x8*)&Al[cb][rowg*16+lm][half*32+lq*8];
            bf16x8 bfr = *(bf16x8*)&Btl[cb][cgrp*16+lm][half*32+lq*8];
            acc = __builtin_amdgcn_mfma_f32_16x16x32_bf16(af, bfr, acc, 0, 0, 0);
        }
        if (ks+1 < nst) {
            int nb = (ks+1) & 1;
            *(uint4*)&Al[nb][rr][kc]  = ra;
            *(uint4*)&Btl[nb][rr][kc] = rb;
        }
    }
    int isbf = dtf[0];
    int n = n0 + cgrp*16 + lm;
    float bia = bias ? ldIn(bias, n, isbf) : 0.f;
    #pragma unroll
    for (int r = 0; r < 4; r++) {
        int m = m0 + rowg*16 + lq*4 + r;
        float v = acc[r] + bia;
        if (act == 1) v = tanhf(v);
        if (obf) ((unsigned short*)C)[(long)m*ldc + n] = f2bf(v);
        else     ((float*)C)[(long)m*ldc + n] = v;
    }
}

// ================= r1 via MFMA, on-the-fly A, double-buffered B =================
// v2: 32-row n-tiles -> grid (64,16)=1024 blocks; hz/tz held in registers
// (no hzL/tzbL LDS) -> LDS = Btl only (32.2KB) -> 4 blocks/CU, 16 waves/CU.
// XCD affinity preserved: blocks sharing a kz slice are {kz + 64*ny}, 64%8==0.
// partial layout unchanged: [n][kz][c]
__global__ void r1_mfma_kernel(const float* __restrict__ hz, const float* __restrict__ tz,
                               const unsigned short* __restrict__ WBt,
                               float* __restrict__ partial) {
    __shared__ unsigned short Btl[2][CPAD_][72];
    int kz = blockIdx.x;
    int n0 = blockIdx.y * 32;
    int kbase = kz * KCHUNK_;
    int gi0 = kbase >> 6;           // hz col base; gi0 = kz*12, 4-aligned
    int g0 = kbase >> 12;           // tz 64-col group base
    int g1 = min(g0 + 1, EMB_/64 - 1);
    int tid = threadIdx.x;
    int wave = tid >> 6, lane = tid & 63;
    int lm = lane & 15, lq = lane >> 4;
    int rowg = wave >> 1;           // 0..1  (16-row group)
    int cgrp = wave & 1;            // 0 -> c-tiles 0..3, 1 -> c-tiles 4..6
    int nrow = n0 + rowg*16 + lm;

    // hz row slice: 12 f32 in registers (statically indexed via full unroll)
    float hv[12];
    {
        const float* hp = hz + (long)nrow*EMB_ + gi0;
        float4 a = *(const float4*)hp;
        float4 b = *(const float4*)(hp+4);
        float4 c = *(const float4*)(hp+8);
        hv[0]=a.x; hv[1]=a.y; hv[2]=a.z;  hv[3]=a.w;
        hv[4]=b.x; hv[5]=b.y; hv[6]=b.z;  hv[7]=b.w;
        hv[8]=c.x; hv[9]=c.y; hv[10]=c.z; hv[11]=c.w;
    }
    // tz fragments for groups g0,g1 x halves, pre-converted to bf16 (16 VGPRs)
    bf16x8 tzb00, tzb01, tzb10, tzb11;
    {
        const float* tp = tz + (long)nrow*EMB_;
        #pragma unroll
        for (int h = 0; h < 2; h++) {
            const float* p0 = tp + g0*64 + h*32 + lq*8;
            const float* p1 = tp + g1*64 + h*32 + lq*8;
            float4 x0 = *(const float4*)p0, y0 = *(const float4*)(p0+4);
            float4 x1 = *(const float4*)p1, y1 = *(const float4*)(p1+4);
            unsigned short o0[8] = {f2bf(x0.x),f2bf(x0.y),f2bf(x0.z),f2bf(x0.w),
                                    f2bf(y0.x),f2bf(y0.y),f2bf(y0.z),f2bf(y0.w)};
            unsigned short o1[8] = {f2bf(x1.x),f2bf(x1.y),f2bf(x1.z),f2bf(x1.w),
                                    f2bf(y1.x),f2bf(y1.y),f2bf(y1.z),f2bf(y1.w)};
            if (h == 0) { tzb00 = *(bf16x8*)o0; tzb10 = *(bf16x8*)o1; }
            else        { tzb01 = *(bf16x8*)o0; tzb11 = *(bf16x8*)o1; }
        }
    }

    // prologue: stage B tile for ks=0
    #pragma unroll
    for (int t = 0; t < 4; t++) {
        int idx = tid + t*256;
        if (idx < 896) {
            int c = idx >> 3, k8 = (idx & 7)*8;
            *(uint4*)&Btl[0][c][k8] = *(const uint4*)(WBt + (long)c*KTOT_ + kbase + k8);
        }
    }

    f32x4 acc[4] = {};
    int nct = 4 - cgrp;             // 4 or 3 c-tiles per wave
    uint4 rb[4];
    #pragma unroll
    for (int ks = 0; ks < KCHUNK_/64; ks++) {
        __syncthreads();
        if (ks+1 < KCHUNK_/64) {
            int k0 = kbase + (ks+1)*64;
            #pragma unroll
            for (int t = 0; t < 4; t++) {
                int idx = tid + t*256;
                if (idx < 896) {
                    int c = idx >> 3, k8 = (idx & 7)*8;
                    rb[t] = *(const uint4*)(WBt + (long)c*KTOT_ + k0 + k8);
                }
            }
        }
        int cb = ks & 1;
        int gs = ((kbase + ks*64) >> 12) > g0;   // wave-uniform group select
        float hvk = hv[ks];
        // A-frag: oa[h] = bf16( tz[h] * hv[ks] )
        unsigned short oa0[8], oa1[8];
        if (gs) {
            #pragma unroll
            for (int e = 0; e < 8; e++) {
                oa0[e] = f2bf(bf2f(((unsigned short*)&tzb10)[e]) * hvk);
                oa1[e] = f2bf(bf2f(((unsigned short*)&tzb11)[e]) * hvk);
            }
        } else {
            #pragma unroll
            for (int e = 0; e < 8; e++) {
                oa0[e] = f2bf(bf2f(((unsigned short*)&tzb00)[e]) * hvk);
                oa1[e] = f2bf(bf2f(((unsigned short*)&tzb01)[e]) * hvk);
            }
        }
        #pragma unroll
        for (int h = 0; h < 2; h++) {
            bf16x8 afrag = (h == 0) ? *(bf16x8*)oa0 : *(bf16x8*)oa1;
            #pragma unroll
            for (int ct = 0; ct < 4; ct++) {
                if (ct < nct) {
                    bf16x8 bfrag = *(bf16x8*)&Btl[cb][(cgrp*4+ct)*16 + lm][h*32 + lq*8];
                    acc[ct] = __builtin_amdgcn_mfma_f32_16x16x32_bf16(afrag, bfrag, acc[ct], 0, 0, 0);
                }
            }
        }
        if (ks+1 < KCHUNK_/64) {
            int nb = (ks+1) & 1;
            #pragma unroll
            for (int t = 0; t < 4; t++) {
                int idx = tid + t*256;
                if (idx < 896) {
                    int c = idx >> 3, k8 = (idx & 7)*8;
                    *(uint4*)&Btl[nb][c][k8] = rb[t];
                }
            }
        }
    }
    #pragma unroll
    for (int ct = 0; ct < 4; ct++) {
        if (ct < nct) {
            int c = (cgrp*4 + ct)*16 + lm;
            #pragma unroll
            for (int r = 0; r < 4; r++) {
                int nl = rowg*16 + lq*4 + r;
                partial[((long)(n0+nl)*KSPLIT_ + kz)*CPAD_ + c] = acc[ct][r];
            }
        }
    }
}

// ---------------- fused: r1 streaming reduce + r2/r3 LSE + final projection ----------------
__global__ void r23out_kernel(const float* __restrict__ partial, const void* __restrict__ b_rel,
                              const float* __restrict__ mu, const float* __restrict__ c23,
                              const int* __restrict__ hts, const int* __restrict__ mention_idx,
                              const float* __restrict__ W_bilF, const void* __restrict__ b_bil,
                              void* __restrict__ out, const int* __restrict__ dtf) {
    int bp = blockIdx.x;
    int b = bp >> 8;
    int c = threadIdx.x;
    int isbf = dtf[0];
    __shared__ float row[292];
    if (c < C_) {
        const float* pr = partial + (long)bp*KSPLIT_*CPAD_;
        float r1v = 0.f;
        #pragma unroll 8
        for (int kz = 0; kz < KSPLIT_; kz++)
            r1v += pr[kz*CPAD_ + c];
        r1v += ldIn(b_rel, c, isbf);
        int h_e = hts[bp*2+0], t_e = hts[bp*2+1];
        const float* mu2h = mu;
        const float* mu2t = mu + 32768;
        const float* mu3h = mu + 65536;
        const float* mu3t = mu + 98304;
        float ah2[4], at2[4], ah3[4], at3[4];
        for (int m = 0; m < 4; m++) {
            int emh = mention_idx[(b*E_ + h_e)*M_ + m];
            int emt = mention_idx[(b*E_ + t_e)*M_ + m];
            ah2[m] = mu2h[(long)(b*128 + emh)*128 + c];
            ah3[m] = mu3h[(long)(b*128 + emh)*128 + c];
            at2[m] = mu2t[(long)(b*128 + emt)*128 + c];
            at3[m] = mu3t[(long)(b*128 + emt)*128 + c];
        }
        float c2 = c23[c], c3 = c23[C_ + c];
        float v2[16], v3[16];
        int q = 0;
        for (int i = 0; i < 4; i++) {
            for (int j = 0; j < 4; j++, q++) {
                float x2 = ah2[i] + at2[j] + c2;
                v2[q] = tanhf(x2);
                float x3 = ah3[i] + at3[j] + c3;
                float t = tanhf(0.7978845608028654f * (x3 + 0.044715f*x3*x3*x3));
                v3[q] = 0.5f * x3 * (1.0f + t);
            }
        }
        float m2 = v2[0], m3 = v3[0];
        for (q = 1; q < 16; q++) { m2 = fmaxf(m2, v2[q]); m3 = fmaxf(m3, v3[q]); }
        float s2 = 0.f, s3 = 0.f;
        for (q = 0; q < 16; q++) { s2 += expf(v2[q]-m2); s3 += expf(v3[q]-m3); }
        row[c]        = r1v;
        row[C_ + c]   = m2 + logf(s2);
        row[2*C_ + c] = m3 + logf(s3);
    }
    __syncthreads();
    if (c >= C_) return;
    float a0 = 0.f, a1 = 0.f, a2 = 0.f, a3 = 0.f;
    #pragma unroll 4
    for (int k = 0; k < 288; k += 4) {
        a0 += row[k+0] * W_bilF[(k+0)*C_ + c];
        a1 += row[k+1] * W_bilF[(k+1)*C_ + c];
        a2 += row[k+2] * W_bilF[(k+2)*C_ + c];
        a3 += row[k+3] * W_bilF[(k+3)*C_ + c];
    }
    a0 += row[288] * W_bilF[288*C_ + c];
    a1 += row[289] * W_bilF[289*C_ + c];
    a2 += row[290] * W_bilF[290*C_ + c];
    float v = a0 + a1 + a2 + a3 + ldIn(b_bil, c, isbf);
    if (isbf) ((bf16*)out)[(long)bp*C_ + c] = (bf16)v;
    else      ((float*)out)[(long)bp*C_ + c] = v;
}

extern "C" void kernel_launch(void* const* d_in, const int* in_sizes, int n_in,
                              void* d_out, int out_size, void* d_ws, size_t ws_size,
                              hipStream_t stream) {
    const void* seq        = d_in[0];
    const void* attn       = d_in[1];
    const int*  entity_pos = (const int*)d_in[2];
    const int*  hts        = (const int*)d_in[3];
    const int*  mention_idx= (const int*)d_in[4];
    const void* W_head     = d_in[5];
    const void* b_head     = d_in[6];
    const void* W_tail     = d_in[7];
    const void* b_tail     = d_in[8];
    const void* W_rel      = d_in[9];
    const void* b_rel      = d_in[10];
    const void* W_fh       = d_in[11];
    const void* W_ft       = d_in[12];
    const void* b_f        = d_in[13];
    const void* W_unet     = d_in[14];
    const void* b_unet     = d_in[15];
    const void* W_mlp      = d_in[16];
    const void* b_mlp      = d_in[17];
    const void* W_bil      = d_in[18];
    const void* b_bil      = d_in[19];

    float* w = (float*)d_ws;
    int*   dtf      = (int*)w;                               // 64
    unsigned short* mentb = (unsigned short*)(w + 64);       // 98304 fl
    float* ent_emb  = w + 98368;                             // 49152
    float* ent_att  = w + 147520;                            // 393216
    unsigned short* htb = (unsigned short*)(w + 540736);     // 131072 fl
    float* rs       = w + 671808;                            // 393216
    float* hz       = w + 1065024;                           // 393216
    float* tz       = w + 1458240;                           // 393216
    float* mu       = w + 1851456;                           // 131072
    float* c23      = w + 1982528;                           // 256
    unsigned short* seqT  = (unsigned short*)(w + 1982784);  // 393216 fl
    unsigned short* WhT   = (unsigned short*)(w + 2376000);  // 589824 fl
    unsigned short* WtT   = (unsigned short*)(w + 2965824);  // 589824 fl
    unsigned short* WfhT  = (unsigned short*)(w + 3555648);  // 294912 fl
    unsigned short* WftT  = (unsigned short*)(w + 3850560);  // 294912 fl
    unsigned short* WunetT= (unsigned short*)(w + 4145472);  // 49152 fl
    unsigned short* WmlpT = (unsigned short*)(w + 4194624);  // 49152 fl
    unsigned short* Tbh   = (unsigned short*)(w + 4243776);  // 98304 fl
    unsigned short* Tbt   = (unsigned short*)(w + 4342080);  // 98304 fl
    unsigned short* hcatb = (unsigned short*)(w + 4440384);  // 393216 fl
    unsigned short* tcatb = (unsigned short*)(w + 4833600);  // 393216 fl
    unsigned short* WBt   = (unsigned short*)(w + 5226816);  // 2752512 fl
    float* partial  = w + 7979328;                           // 3670016 fl
    float* W_bilF   = w + 11649344;                          // 28227 fl

    // 0. dtype detection + c23 init
    dtype_detect<<<1, 256, 0, stream>>>(seq, dtf, c23);
    // 1. prep: transposes + W_bilF + c23 + W_rel conv
    {
        PrepArgs a = {};
        const void* srcs[8] = {W_head, W_tail, W_fh, W_ft, W_unet, W_mlp, seq, seq};
        long offs[8]   = {0,0,0,0,0,0,0,393216};
        int Ks[8]      = {1536,1536,768,768,768,768,512,512};
        int Ncols8[8]  = {768,768,768,768,97,97,768,768};
        int Npads[8]   = {768,768,768,768,128,128,768,768};
        unsigned short* dsts[8] = {WhT, WtT, WfhT, WftT, WunetT, WmlpT, seqT, seqT+393216};
        for (int z = 0; z < 8; z++) {
            a.src[z]=srcs[z]; a.off[z]=offs[z]; a.K[z]=Ks[z];
            a.Ncols[z]=Ncols8[z]; a.Npad[z]=Npads[z]; a.dst[z]=dsts[z];
        }
        a.W_bil = W_bil; a.W_bilF = W_bilF;
        a.b_f = b_f; a.W_unet = W_unet; a.b_unet = b_unet;
        a.W_mlp = W_mlp; a.b_mlp = b_mlp; a.c23 = c23;
        a.W_rel = W_rel; a.WBt = WBt;
        prep_kernel<<<dim3(48, 16, 11), 256, 0, stream>>>(a, dtf);
    }
    // 2. gather: entatt + ment
    gather_kernel<<<768 + 64, 256, 0, stream>>>(seq, attn, entity_pos, mentb, ent_emb, ent_att, dtf);
    // 3. ht attention (normalized, bf16)
    htatt_kernel<<<N_, 256, 0, stream>>>(ent_att, hts, htb);
    // 4. gemmA: rs (z=0,1) + T_{h,t} (z=2,3)  [32x32 tiles: M=256 -> 8, N=768 -> 24]
    {
        MfmaJob ga = {};
        for (int z = 0; z < 2; z++) {
            ga.A[z] = htb + (long)z*256*512; ga.Bt[z] = seqT + (long)z*393216;
            ga.bias[z] = nullptr; ga.C[z] = rs + (long)z*256*768;
            ga.K[z] = 512; ga.ldc[z] = 768; ga.act[z] = 0; ga.obf[z] = 0;
        }
        ga.A[2] = mentb; ga.Bt[2] = WfhT; ga.bias[2] = nullptr; ga.C[2] = Tbh;
        ga.K[2] = 768; ga.ldc[2] = 768; ga.act[2] = 0; ga.obf[2] = 1;
        ga.A[3] = mentb; ga.Bt[3] = WftT; ga.bias[3] = nullptr; ga.C[3] = Tbt;
        ga.K[3] = 768; ga.ldc[3] = 768; ga.act[3] = 0; ga.obf[3] = 1;
        mfma_nt2_kernel<<<dim3(8, 24, 4), 256, 0, stream>>>(ga, dtf);
    }
    // 5. concatenated inputs (bf16)
    catb_kernel<<<N_, 256, 0, stream>>>(ent_emb, rs, hts, hcatb, tcatb);
    // 6. gemmB: hz/tz = tanh(cat @ W + b)  [M=512 -> 16, N=768 -> 24]
    {
        MfmaJob ga = {};
        ga.A[0] = hcatb; ga.Bt[0] = WhT; ga.bias[0] = b_head; ga.C[0] = hz;
        ga.A[1] = tcatb; ga.Bt[1] = WtT; ga.bias[1] = b_tail; ga.C[1] = tz;
        for (int z = 0; z < 2; z++) { ga.K[z] = 1536; ga.ldc[z] = 768; ga.act[z] = 1; ga.obf[z] = 0; }
        mfma_nt2_kernel<<<dim3(16, 24, 2), 256, 0, stream>>>(ga, dtf);
    }
    // 7. gemmC: mu_q = T @ W_{unet,mlp}  [M=256 -> 8, N=128 -> 4]
    {
        MfmaJob ga = {};
        const unsigned short* As[4] = {Tbh, Tbt, Tbh, Tbt};
        const unsigned short* Bs[4] = {WunetT, WunetT, WmlpT, WmlpT};
        for (int q = 0; q < 4; q++) {
            ga.A[q] = As[q]; ga.Bt[q] = Bs[q]; ga.bias[q] = nullptr;
            ga.C[q] = mu + q*32768;
            ga.K[q] = 768; ga.ldc[q] = 128; ga.act[q] = 0; ga.obf[q] = 0;
        }
        mfma_nt2_kernel<<<dim3(8, 4, 4), 256, 0, stream>>>(ga, dtf);
    }
    // 8. r1 partials via MFMA (kz-fastest grid for XCD slice affinity; 32-row n-tiles)
    r1_mfma_kernel<<<dim3(KSPLIT_, 16), 256, 0, stream>>>(hz, tz, WBt, partial);
    // 9. fused reduce + r2/r3 + final projection
    r23out_kernel<<<N_, 128, 0, stream>>>(partial, b_rel, mu, c23, hts, mention_idx,
                                          W_bilF, b_bil, d_out, dtf);
}

// Round 4
// 272.572 us; speedup vs baseline: 1.0035x; 1.0035x over previous
//
#include <hip/hip_runtime.h>
#include <hip/hip_bf16.h>

// Problem constants
#define B_  2
#define L_  512
#define D_  768
#define H_  12
#define E_  32
#define M_  4
#define P_  256
#define EMB_ 768
#define BS_ 64
#define C_  97
#define N_  (B_*P_)   // 512

#define KTOT_    49152      // EMB*BS
#define CPAD_    112        // 97 padded to 7*16
#define KSPLIT_  48
#define KCHUNK_  (KTOT_/KSPLIT_)   // 1024, 16 ks-steps of 64; divides 4096 -> no group crossing
#define PSTR_    128        // partial chunk stride (floats): 512 B, cache-line exclusive

typedef __hip_bfloat16 bf16;
typedef __attribute__((ext_vector_type(8))) short bf16x8;
typedef __attribute__((ext_vector_type(4))) float f32x4;
typedef __attribute__((ext_vector_type(8))) float f32x8;

__device__ inline float ldIn(const void* p, long idx, int isbf) {
    return isbf ? (float)((const bf16*)p)[idx] : ((const float*)p)[idx];
}

__device__ inline unsigned short f2bf(float f) {
    bf16 h = (bf16)f;
    return *(unsigned short*)&h;
}

__device__ inline float bf2f(unsigned short u) {
    bf16 h = *(bf16*)&u;
    return (float)h;
}

// ---------------- K0: dtype detection + c23 zero-init ----------------
__global__ void dtype_detect(const void* __restrict__ seq, int* __restrict__ flag,
                             float* __restrict__ c23) {
    __shared__ int cnt;
    if (threadIdx.x == 0) cnt = 0;
    if (threadIdx.x < 2*C_) c23[threadIdx.x] = 0.f;
    __syncthreads();
    const unsigned short* u = (const unsigned short*)seq;
    int bad = 0;
    for (int i = threadIdx.x; i < 1024; i += 256) {
        unsigned short e = (u[i] >> 7) & 0xFF;
        if (e >= 140) bad++;
    }
    atomicAdd(&cnt, bad);
    __syncthreads();
    if (threadIdx.x == 0) flag[0] = (cnt < 16) ? 1 : 0;   // 1 = bf16 inputs
}

// ---------------- prep: z<8 transposes (32k x 64n), z=8 W_bil->f32, z=9 c23, z=10 W_rel conv ----
struct PrepArgs {
    const void* src[8];
    long off[8];
    int K[8];
    int Ncols[8];
    int Npad[8];
    unsigned short* dst[8];
    const void* W_bil;  float* W_bilF;
    const void* b_f; const void* W_unet; const void* b_unet;
    const void* W_mlp; const void* b_mlp; float* c23;
    const void* W_rel; unsigned short* WBt;
};

union PrepSm {
    float T[32][65];                 // 8320 B
    unsigned short TW[CPAD_][72];    // 16128 B
};

__global__ void prep_kernel(PrepArgs a, const int* __restrict__ dtf) {
    int isbf = dtf[0];
    int z = blockIdx.z;
    __shared__ PrepSm sm;
    int tid = threadIdx.x;
    if (z < 8) {
        int K = a.K[z], Ncols = a.Ncols[z], Npad = a.Npad[z];
        int k0 = blockIdx.x*32, n0 = blockIdx.y*64;
        if (k0 >= K || n0 >= Npad) return;
        const void* src = a.src[z];
        long off = a.off[z];
        unsigned short* dst = a.dst[z];
        // read: 64 consecutive cols per row (coalesced 128/256 B)
        int c64 = tid & 63, r4 = tid >> 6;
        for (int p = 0; p < 8; p++) {
            int r = r4 + p*4;
            int n = n0 + c64;
            sm.T[r][c64] = (n < Ncols) ? ldIn(src, off + (long)(k0+r)*Ncols + n, isbf) : 0.f;
        }
        __syncthreads();
        // write: 32 consecutive k per n (coalesced)
        int cc = tid & 31, n8 = tid >> 5;
        for (int p = 0; p < 8; p++) {
            int nn = n8 + p*8;
            dst[(long)(n0+nn)*K + k0 + cc] = f2bf(sm.T[cc][nn]);
        }
    } else if (z == 8) {
        int lin = blockIdx.y*48 + blockIdx.x;
        int idx = lin*256 + tid;
        if (idx < 291*C_) a.W_bilF[idx] = ldIn(a.W_bil, idx, isbf);
    } else if (z == 9) {
        // c23 partial: 8 blocks x 96 d-rows, coalesced over c, atomic accumulate
        int lin = blockIdx.y*48 + blockIdx.x;
        if (lin >= 8) return;
        int c = tid;
        if (c >= C_) return;
        float s2 = 0.f, s3 = 0.f;
        int d0 = lin*96;
        for (int i = 0; i < 96; i++) {
            int d = d0 + i;
            float bf = ldIn(a.b_f, d, isbf);
            s2 += bf * ldIn(a.W_unet, (long)d*C_ + c, isbf);
            s3 += bf * ldIn(a.W_mlp,  (long)d*C_ + c, isbf);
        }
        if (lin == 0) {
            s2 += ldIn(a.b_unet, c, isbf);
            s3 += ldIn(a.b_mlp,  c, isbf);
        }
        atomicAdd(&a.c23[c], s2);
        atomicAdd(&a.c23[C_ + c], s3);
    } else {
        // W_rel -> WBt[c][k] bf16, c padded to 112; 64-k tiles
        int lin = blockIdx.y*48 + blockIdx.x;
        if (lin >= KTOT_/64) return;
        int k0 = lin * 64;
        for (int idx = tid; idx < 64*97; idx += 256) {
            int kk = idx / 97, c = idx % 97;
            sm.TW[c][kk] = f2bf(ldIn(a.W_rel, (long)(k0+kk)*C_ + c, isbf));
        }
        for (int idx = tid; idx < 15*64; idx += 256) {
            sm.TW[97 + (idx>>6)][idx & 63] = 0;
        }
        __syncthreads();
        for (int t = 0; t < 4; t++) {
            int idx = tid + t*256;      // < 896 = 112*8
            if (idx < 896) {
                int c = idx >> 3, kc = idx & 7;
                *(uint4*)(a.WBt + (long)c*KTOT_ + k0 + kc*8) = *(uint4*)&sm.TW[c][kc*8];
            }
        }
    }
}

// ---------------- gather: bx<768 entatt, else ment ----------------
__global__ void gather_kernel(const void* __restrict__ seq, const void* __restrict__ attn,
                              const int* __restrict__ entity_pos,
                              unsigned short* __restrict__ mentb, float* __restrict__ ent_emb,
                              float* __restrict__ ent_att, const int* __restrict__ dtf) {
    int isbf = dtf[0];
    if (blockIdx.x < 768) {
        int beh = blockIdx.x;
        int h = beh % H_;
        int be = beh / H_;
        int b = be >> 5;
        int pos[M_];
        for (int m = 0; m < M_; m++) pos[m] = entity_pos[be*M_+m] + 1;
        for (int l = threadIdx.x; l < L_; l += 256) {
            float s = 0.f;
            for (int m = 0; m < M_; m++)
                s += ldIn(attn, (((long)(b*H_ + h))*L_ + pos[m])*L_ + l, isbf);
            ent_att[(long)beh*L_ + l] = 0.25f * s;
        }
    } else {
        int be = blockIdx.x - 768;     // 0..63
        int b = be >> 5;
        int pos[M_];
        for (int m = 0; m < M_; m++) pos[m] = entity_pos[be*M_+m] + 1;
        for (int d = threadIdx.x; d < D_; d += 256) {
            float x[M_];
            for (int m = 0; m < M_; m++) {
                x[m] = ldIn(seq, ((long)b*L_ + pos[m])*D_ + d, isbf);
                mentb[((long)be*M_ + m)*D_ + d] = f2bf(x[m]);
            }
            float mx = fmaxf(fmaxf(x[0],x[1]), fmaxf(x[2],x[3]));
            float s = expf(x[0]-mx)+expf(x[1]-mx)+expf(x[2]-mx)+expf(x[3]-mx);
            ent_emb[(long)be*D_ + d] = mx + logf(s);
        }
    }
}

// ---------------- K3: ht_att (bf16) = normalize_L( mean_H(ha*ta) ) ----------------
__global__ void htatt_kernel(const float* __restrict__ ent_att, const int* __restrict__ hts,
                             unsigned short* __restrict__ htb) {
    int bp = blockIdx.x;            // 512 blocks
    int b = bp >> 8;
    int h_e = hts[bp*2+0], t_e = hts[bp*2+1];
    const float* ea_h = ent_att + (long)((b*E_ + h_e)*H_)*L_;
    const float* ea_t = ent_att + (long)((b*E_ + t_e)*H_)*L_;
    __shared__ float red[256];
    float v[2];
    for (int t = 0; t < 2; t++) {
        int l = threadIdx.x + t*256;
        float s = 0.f;
        for (int h = 0; h < H_; h++) s += ea_h[h*L_+l] * ea_t[h*L_+l];
        v[t] = s * (1.0f/H_);
    }
    red[threadIdx.x] = v[0] + v[1];
    __syncthreads();
    for (int off = 128; off > 0; off >>= 1) {
        if (threadIdx.x < off) red[threadIdx.x] += red[threadIdx.x+off];
        __syncthreads();
    }
    float inv = 1.0f / (red[0] + 1e-5f);
    for (int t = 0; t < 2; t++) {
        int l = threadIdx.x + t*256;
        htb[(long)bp*L_ + l] = f2bf(v[t] * inv);
    }
}

// ---------------- catb: hcatb=[hs,rs], tcatb=[ts,rs] in bf16 ----------------
__global__ void catb_kernel(const float* __restrict__ ent_emb, const float* __restrict__ rs,
                            const int* __restrict__ hts,
                            unsigned short* __restrict__ hcatb, unsigned short* __restrict__ tcatb) {
    int n = blockIdx.x;             // 512
    int b = n >> 8;
    int h_e = hts[n*2+0], t_e = hts[n*2+1];
    const float* eh = ent_emb + (long)(b*E_ + h_e)*D_;
    const float* et = ent_emb + (long)(b*E_ + t_e)*D_;
    const float* r  = rs + (long)n*D_;
    for (int k = threadIdx.x; k < D_; k += 256) {
        hcatb[(long)n*1536 + k] = f2bf(eh[k]);
        tcatb[(long)n*1536 + k] = f2bf(et[k]);
        unsigned short rb = f2bf(r[k]);
        hcatb[(long)n*1536 + 768 + k] = rb;
        tcatb[(long)n*1536 + 768 + k] = rb;
    }
}

// ---------------- Generic MFMA GEMM (double-buffered), 32x32 tiles ----------------
struct MfmaJob {
    const unsigned short* A[4];
    const unsigned short* Bt[4];
    const void* bias[4];
    void* C[4];
    int K[4];
    int ldc[4];
    int act[4];
    int obf[4];
};

__global__ void mfma_nt2_kernel(MfmaJob args, const int* __restrict__ dtf) {
    int z = blockIdx.z;
    const unsigned short* A  = args.A[z];
    const unsigned short* Bt = args.Bt[z];
    const void* bias = args.bias[z];
    void* C = args.C[z];
    int K = args.K[z], ldc = args.ldc[z], act = args.act[z], obf = args.obf[z];
    __shared__ unsigned short Al[2][32][72];
    __shared__ unsigned short Btl[2][32][72];
    int m0 = blockIdx.x*32, n0 = blockIdx.y*32;
    int tid = threadIdx.x, wave = tid>>6, lane = tid&63;
    int lm = lane&15, lq = lane>>4;
    int rowg = wave>>1, cgrp = wave&1;   // wave -> (row half, col half)
    int rr = tid >> 3;                // 0..31
    int kc = (tid & 7) * 8;           // col offset in ushorts
    uint4 ra, rb;

    ra = *(const uint4*)(A  + (long)(m0+rr)*K + kc);
    rb = *(const uint4*)(Bt + (long)(n0+rr)*K + kc);
    *(uint4*)&Al[0][rr][kc]  = ra;
    *(uint4*)&Btl[0][rr][kc] = rb;

    int nst = K >> 6;
    f32x4 acc = {};
    for (int ks = 0; ks < nst; ks++) {
        __syncthreads();
        if (ks+1 < nst) {
            int k0 = (ks+1) << 6;
            ra = *(const uint4*)(A  + (long)(m0+rr)*K + k0 + kc);
            rb = *(const uint4*)(Bt + (long)(n0+rr)*K + k0 + kc);
        }
        int cb = ks & 1;
        #pragma unroll
        for (int half = 0; half < 2; half++) {
            bf16x8 af  = *(bf16x8*)&Al[cb][rowg*16+lm][half*32+lq*8];
            bf16x8 bfr = *(bf16x8*)&Btl[cb][cgrp*16+lm][half*32+lq*8];
            acc = __builtin_amdgcn_mfma_f32_16x16x32_bf16(af, bfr, acc, 0, 0, 0);
        }
        if (ks+1 < nst) {
            int nb = (ks+1) & 1;
            *(uint4*)&Al[nb][rr][kc]  = ra;
            *(uint4*)&Btl[nb][rr][kc] = rb;
        }
    }
    int isbf = dtf[0];
    int n = n0 + cgrp*16 + lm;
    float bia = bias ? ldIn(bias, n, isbf) : 0.f;
    #pragma unroll
    for (int r = 0; r < 4; r++) {
        int m = m0 + rowg*16 + lq*4 + r;
        float v = acc[r] + bia;
        if (act == 1) v = tanhf(v);
        if (obf) ((unsigned short*)C)[(long)m*ldc + n] = f2bf(v);
        else     ((float*)C)[(long)m*ldc + n] = v;
    }
}

// ================= r1 via MFMA, on-the-fly A, double-buffered B =================
// v3b: KSPLIT=48, KCHUNK=1024 (16 steps of 64). 1024 | 4096 -> a chunk never
// crosses a tz 64-col group: single f32 tz fragment, no group select. hz tile
// in LDS (stride 17, conflict-free). Partial chunks padded to 128 floats
// (512 B): cache-line-exclusive per block -> kills the cross-XCD RMW write
// amplification seen in v2 (WRITE_SIZE 77 MB on 14.7 MB ideal).
// ks loop unroll capped at 2 (parity for the double buffer) -- the v3 full
// 16x unroll was the prime suspect for the build/run pipeline failure.
__global__ __launch_bounds__(256, 3)
void r1_mfma_kernel(const float* __restrict__ hz, const float* __restrict__ tz,
                    const unsigned short* __restrict__ WBt,
                    float* __restrict__ partial) {
    __shared__ unsigned short Btl[2][CPAD_][72];
    __shared__ float hzL[32][17];
    int kz = blockIdx.x;
    int n0 = blockIdx.y * 32;
    int kbase = kz * KCHUNK_;
    int gi0 = kbase >> 6;            // hz col base = kz*16
    int g0 = kbase >> 12;            // tz group, fixed for the whole chunk
    int tid = threadIdx.x;
    int wave = tid >> 6, lane = tid & 63;
    int lm = lane & 15, lq = lane >> 4;
    int rowg = wave >> 1;            // 0..1  (16-row group)
    int cgrp = wave & 1;             // 0 -> c-tiles 0..3, 1 -> c-tiles 4..6
    int nrow = n0 + rowg*16 + lm;

    // hz tile 32 rows x 16 cols -> LDS (512 elems, 2 per thread)
    {
        int r = tid >> 3, q = (tid & 7) * 2;
        float2 v = *(const float2*)(hz + (long)(n0 + r)*EMB_ + gi0 + q);
        hzL[r][q] = v.x; hzL[r][q+1] = v.y;
    }
    // tz fragment for this row, f32 (16 regs): cols g0*64 + half*32 + lq*8 + e
    f32x8 t0, t1;
    {
        const float* tp = tz + (long)nrow*EMB_ + g0*64;
        float4 a = *(const float4*)(tp + lq*8);
        float4 b = *(const float4*)(tp + lq*8 + 4);
        float4 c = *(const float4*)(tp + 32 + lq*8);
        float4 d = *(const float4*)(tp + 32 + lq*8 + 4);
        t0[0]=a.x; t0[1]=a.y; t0[2]=a.z; t0[3]=a.w;
        t0[4]=b.x; t0[5]=b.y; t0[6]=b.z; t0[7]=b.w;
        t1[0]=c.x; t1[1]=c.y; t1[2]=c.z; t1[3]=c.w;
        t1[4]=d.x; t1[5]=d.y; t1[6]=d.z; t1[7]=d.w;
    }

    // prologue: stage B tile for ks=0
    #pragma unroll
    for (int t = 0; t < 4; t++) {
        int idx = tid + t*256;
        if (idx < 896) {
            int c = idx >> 3, k8 = (idx & 7)*8;
            *(uint4*)&Btl[0][c][k8] = *(const uint4*)(WBt + (long)c*KTOT_ + kbase + k8);
        }
    }

    f32x4 acc[4] = {};
    int nct = 4 - cgrp;             // 4 or 3 c-tiles per wave
    uint4 rb[4];
    #pragma unroll 2
    for (int ks = 0; ks < KCHUNK_/64; ks++) {
        __syncthreads();
        if (ks+1 < KCHUNK_/64) {
            int k0 = kbase + (ks+1)*64;
            #pragma unroll
            for (int t = 0; t < 4; t++) {
                int idx = tid + t*256;
                if (idx < 896) {
                    int c = idx >> 3, k8 = (idx & 7)*8;
                    rb[t] = *(const uint4*)(WBt + (long)c*KTOT_ + k0 + k8);
                }
            }
        }
        int cb = ks & 1;
        float hvk = hzL[rowg*16 + lm][ks];
        // A-frag: oa[h] = bf16( tz[h] * hv[ks] )  (2 VALU/elem: mul + cvt)
        unsigned short oa0[8], oa1[8];
        #pragma unroll
        for (int e = 0; e < 8; e++) {
            oa0[e] = f2bf(t0[e] * hvk);
            oa1[e] = f2bf(t1[e] * hvk);
        }
        #pragma unroll
        for (int h = 0; h < 2; h++) {
            bf16x8 afrag = (h == 0) ? *(bf16x8*)oa0 : *(bf16x8*)oa1;
            #pragma unroll
            for (int ct = 0; ct < 4; ct++) {
                if (ct < nct) {
                    bf16x8 bfrag = *(bf16x8*)&Btl[cb][(cgrp*4+ct)*16 + lm][h*32 + lq*8];
                    acc[ct] = __builtin_amdgcn_mfma_f32_16x16x32_bf16(afrag, bfrag, acc[ct], 0, 0, 0);
                }
            }
        }
        if (ks+1 < KCHUNK_/64) {
            int nb = (ks+1) & 1;
            #pragma unroll
            for (int t = 0; t < 4; t++) {
                int idx = tid + t*256;
                if (idx < 896) {
                    int c = idx >> 3, k8 = (idx & 7)*8;
                    *(uint4*)&Btl[nb][c][k8] = rb[t];
                }
            }
        }
    }
    #pragma unroll
    for (int ct = 0; ct < 4; ct++) {
        if (ct < nct) {
            int c = (cgrp*4 + ct)*16 + lm;
            #pragma unroll
            for (int r = 0; r < 4; r++) {
                int nl = rowg*16 + lq*4 + r;
                partial[((long)(n0+nl)*KSPLIT_ + kz)*PSTR_ + c] = acc[ct][r];
            }
        }
    }
}

// ---------------- fused: r1 streaming reduce + r2/r3 LSE + final projection ----------------
__global__ void r23out_kernel(const float* __restrict__ partial, const void* __restrict__ b_rel,
                              const float* __restrict__ mu, const float* __restrict__ c23,
                              const int* __restrict__ hts, const int* __restrict__ mention_idx,
                              const float* __restrict__ W_bilF, const void* __restrict__ b_bil,
                              void* __restrict__ out, const int* __restrict__ dtf) {
    int bp = blockIdx.x;
    int b = bp >> 8;
    int c = threadIdx.x;
    int isbf = dtf[0];
    __shared__ float row[292];
    if (c < C_) {
        const float* pr = partial + (long)bp*KSPLIT_*PSTR_;
        float r1v = 0.f;
        #pragma unroll 8
        for (int kz = 0; kz < KSPLIT_; kz++)
            r1v += pr[kz*PSTR_ + c];
        r1v += ldIn(b_rel, c, isbf);
        int h_e = hts[bp*2+0], t_e = hts[bp*2+1];
        const float* mu2h = mu;
        const float* mu2t = mu + 32768;
        const float* mu3h = mu + 65536;
        const float* mu3t = mu + 98304;
        float ah2[4], at2[4], ah3[4], at3[4];
        for (int m = 0; m < 4; m++) {
            int emh = mention_idx[(b*E_ + h_e)*M_ + m];
            int emt = mention_idx[(b*E_ + t_e)*M_ + m];
            ah2[m] = mu2h[(long)(b*128 + emh)*128 + c];
            ah3[m] = mu3h[(long)(b*128 + emh)*128 + c];
            at2[m] = mu2t[(long)(b*128 + emt)*128 + c];
            at3[m] = mu3t[(long)(b*128 + emt)*128 + c];
        }
        float c2 = c23[c], c3 = c23[C_ + c];
        float v2[16], v3[16];
        int q = 0;
        for (int i = 0; i < 4; i++) {
            for (int j = 0; j < 4; j++, q++) {
                float x2 = ah2[i] + at2[j] + c2;
                v2[q] = tanhf(x2);
                float x3 = ah3[i] + at3[j] + c3;
                float t = tanhf(0.7978845608028654f * (x3 + 0.044715f*x3*x3*x3));
                v3[q] = 0.5f * x3 * (1.0f + t);
            }
        }
        float m2 = v2[0], m3 = v3[0];
        for (q = 1; q < 16; q++) { m2 = fmaxf(m2, v2[q]); m3 = fmaxf(m3, v3[q]); }
        float s2 = 0.f, s3 = 0.f;
        for (q = 0; q < 16; q++) { s2 += expf(v2[q]-m2); s3 += expf(v3[q]-m3); }
        row[c]        = r1v;
        row[C_ + c]   = m2 + logf(s2);
        row[2*C_ + c] = m3 + logf(s3);
    }
    __syncthreads();
    if (c >= C_) return;
    float a0 = 0.f, a1 = 0.f, a2 = 0.f, a3 = 0.f;
    #pragma unroll 4
    for (int k = 0; k < 288; k += 4) {
        a0 += row[k+0] * W_bilF[(k+0)*C_ + c];
        a1 += row[k+1] * W_bilF[(k+1)*C_ + c];
        a2 += row[k+2] * W_bilF[(k+2)*C_ + c];
        a3 += row[k+3] * W_bilF[(k+3)*C_ + c];
    }
    a0 += row[288] * W_bilF[288*C_ + c];
    a1 += row[289] * W_bilF[289*C_ + c];
    a2 += row[290] * W_bilF[290*C_ + c];
    float v = a0 + a1 + a2 + a3 + ldIn(b_bil, c, isbf);
    if (isbf) ((bf16*)out)[(long)bp*C_ + c] = (bf16)v;
    else      ((float*)out)[(long)bp*C_ + c] = v;
}

extern "C" void kernel_launch(void* const* d_in, const int* in_sizes, int n_in,
                              void* d_out, int out_size, void* d_ws, size_t ws_size,
                              hipStream_t stream) {
    const void* seq        = d_in[0];
    const void* attn       = d_in[1];
    const int*  entity_pos = (const int*)d_in[2];
    const int*  hts        = (const int*)d_in[3];
    const int*  mention_idx= (const int*)d_in[4];
    const void* W_head     = d_in[5];
    const void* b_head     = d_in[6];
    const void* W_tail     = d_in[7];
    const void* b_tail     = d_in[8];
    const void* W_rel      = d_in[9];
    const void* b_rel      = d_in[10];
    const void* W_fh       = d_in[11];
    const void* W_ft       = d_in[12];
    const void* b_f        = d_in[13];
    const void* W_unet     = d_in[14];
    const void* b_unet     = d_in[15];
    const void* W_mlp      = d_in[16];
    const void* b_mlp      = d_in[17];
    const void* W_bil      = d_in[18];
    const void* b_bil      = d_in[19];

    float* w = (float*)d_ws;
    int*   dtf      = (int*)w;                               // 64
    unsigned short* mentb = (unsigned short*)(w + 64);       // 98304 fl
    float* ent_emb  = w + 98368;                             // 49152
    float* ent_att  = w + 147520;                            // 393216
    unsigned short* htb = (unsigned short*)(w + 540736);     // 131072 fl
    float* rs       = w + 671808;                            // 393216
    float* hz       = w + 1065024;                           // 393216
    float* tz       = w + 1458240;                           // 393216
    float* mu       = w + 1851456;                           // 131072
    float* c23      = w + 1982528;                           // 256
    unsigned short* seqT  = (unsigned short*)(w + 1982784);  // 393216 fl
    unsigned short* WhT   = (unsigned short*)(w + 2376000);  // 589824 fl
    unsigned short* WtT   = (unsigned short*)(w + 2965824);  // 589824 fl
    unsigned short* WfhT  = (unsigned short*)(w + 3555648);  // 294912 fl
    unsigned short* WftT  = (unsigned short*)(w + 3850560);  // 294912 fl
    unsigned short* WunetT= (unsigned short*)(w + 4145472);  // 49152 fl
    unsigned short* WmlpT = (unsigned short*)(w + 4194624);  // 49152 fl
    unsigned short* Tbh   = (unsigned short*)(w + 4243776);  // 98304 fl
    unsigned short* Tbt   = (unsigned short*)(w + 4342080);  // 98304 fl
    unsigned short* hcatb = (unsigned short*)(w + 4440384);  // 393216 fl
    unsigned short* tcatb = (unsigned short*)(w + 4833600);  // 393216 fl
    unsigned short* WBt   = (unsigned short*)(w + 5226816);  // 2752512 fl
    float* partial  = w + 7979328;                           // 3670016 fl (used: 512*48*128 = 3145728)
    float* W_bilF   = w + 11649344;                          // 28227 fl

    // 0. dtype detection + c23 init
    dtype_detect<<<1, 256, 0, stream>>>(seq, dtf, c23);
    // 1. prep: transposes + W_bilF + c23 + W_rel conv
    {
        PrepArgs a = {};
        const void* srcs[8] = {W_head, W_tail, W_fh, W_ft, W_unet, W_mlp, seq, seq};
        long offs[8]   = {0,0,0,0,0,0,0,393216};
        int Ks[8]      = {1536,1536,768,768,768,768,512,512};
        int Ncols8[8]  = {768,768,768,768,97,97,768,768};
        int Npads[8]   = {768,768,768,768,128,128,768,768};
        unsigned short* dsts[8] = {WhT, WtT, WfhT, WftT, WunetT, WmlpT, seqT, seqT+393216};
        for (int z = 0; z < 8; z++) {
            a.src[z]=srcs[z]; a.off[z]=offs[z]; a.K[z]=Ks[z];
            a.Ncols[z]=Ncols8[z]; a.Npad[z]=Npads[z]; a.dst[z]=dsts[z];
        }
        a.W_bil = W_bil; a.W_bilF = W_bilF;
        a.b_f = b_f; a.W_unet = W_unet; a.b_unet = b_unet;
        a.W_mlp = W_mlp; a.b_mlp = b_mlp; a.c23 = c23;
        a.W_rel = W_rel; a.WBt = WBt;
        prep_kernel<<<dim3(48, 16, 11), 256, 0, stream>>>(a, dtf);
    }
    // 2. gather: entatt + ment
    gather_kernel<<<768 + 64, 256, 0, stream>>>(seq, attn, entity_pos, mentb, ent_emb, ent_att, dtf);
    // 3. ht attention (normalized, bf16)
    htatt_kernel<<<N_, 256, 0, stream>>>(ent_att, hts, htb);
    // 4. gemmA: rs (z=0,1) + T_{h,t} (z=2,3)  [32x32 tiles]
    {
        MfmaJob ga = {};
        for (int z = 0; z < 2; z++) {
            ga.A[z] = htb + (long)z*256*512; ga.Bt[z] = seqT + (long)z*393216;
            ga.bias[z] = nullptr; ga.C[z] = rs + (long)z*256*768;
            ga.K[z] = 512; ga.ldc[z] = 768; ga.act[z] = 0; ga.obf[z] = 0;
        }
        ga.A[2] = mentb; ga.Bt[2] = WfhT; ga.bias[2] = nullptr; ga.C[2] = Tbh;
        ga.K[2] = 768; ga.ldc[2] = 768; ga.act[2] = 0; ga.obf[2] = 1;
        ga.A[3] = mentb; ga.Bt[3] = WftT; ga.bias[3] = nullptr; ga.C[3] = Tbt;
        ga.K[3] = 768; ga.ldc[3] = 768; ga.act[3] = 0; ga.obf[3] = 1;
        mfma_nt2_kernel<<<dim3(8, 24, 4), 256, 0, stream>>>(ga, dtf);
    }
    // 5. concatenated inputs (bf16)
    catb_kernel<<<N_, 256, 0, stream>>>(ent_emb, rs, hts, hcatb, tcatb);
    // 6. gemmB: hz/tz = tanh(cat @ W + b)
    {
        MfmaJob ga = {};
        ga.A[0] = hcatb; ga.Bt[0] = WhT; ga.bias[0] = b_head; ga.C[0] = hz;
        ga.A[1] = tcatb; ga.Bt[1] = WtT; ga.bias[1] = b_tail; ga.C[1] = tz;
        for (int z = 0; z < 2; z++) { ga.K[z] = 1536; ga.ldc[z] = 768; ga.act[z] = 1; ga.obf[z] = 0; }
        mfma_nt2_kernel<<<dim3(16, 24, 2), 256, 0, stream>>>(ga, dtf);
    }
    // 7. gemmC: mu_q = T @ W_{unet,mlp}
    {
        MfmaJob ga = {};
        const unsigned short* As[4] = {Tbh, Tbt, Tbh, Tbt};
        const unsigned short* Bs[4] = {WunetT, WunetT, WmlpT, WmlpT};
        for (int q = 0; q < 4; q++) {
            ga.A[q] = As[q]; ga.Bt[q] = Bs[q]; ga.bias[q] = nullptr;
            ga.C[q] = mu + q*32768;
            ga.K[q] = 768; ga.ldc[q] = 128; ga.act[q] = 0; ga.obf[q] = 0;
        }
        mfma_nt2_kernel<<<dim3(8, 4, 4), 256, 0, stream>>>(ga, dtf);
    }
    // 8. r1 partials via MFMA (kz-fastest grid for XCD slice affinity; 32-row n-tiles)
    r1_mfma_kernel<<<dim3(KSPLIT_, 16), 256, 0, stream>>>(hz, tz, WBt, partial);
    // 9. fused reduce + r2/r3 + final projection
    r23out_kernel<<<N_, 128, 0, stream>>>(partial, b_rel, mu, c23, hts, mention_idx,
                                          W_bilF, b_bil, d_out, dtf);
}

// Round 5
// 270.501 us; speedup vs baseline: 1.0112x; 1.0077x over previous
//
#include <hip/hip_runtime.h>
#include <hip/hip_bf16.h>

// Problem constants
#define B_  2
#define L_  512
#define D_  768
#define H_  12
#define E_  32
#define M_  4
#define P_  256
#define EMB_ 768
#define BS_ 64
#define C_  97
#define N_  (B_*P_)   // 512

#define KTOT_    49152      // EMB*BS
#define CPAD_    112        // 97 padded to 7*16
#define KSPLIT_  48
#define KCHUNK_  (KTOT_/KSPLIT_)   // 1024, 16 ks-steps of 64; divides 4096 -> no group crossing
#define PSTR_    128        // partial chunk stride (floats): 512 B, cache-line exclusive
#define TILE_    (CPAD_*64) // 7168 ushorts = 14336 B per k-step tile of WBt

typedef __hip_bfloat16 bf16;
typedef __attribute__((ext_vector_type(8))) short bf16x8;
typedef __attribute__((ext_vector_type(4))) float f32x4;
typedef __attribute__((ext_vector_type(8))) float f32x8;

__device__ inline float ldIn(const void* p, long idx, int isbf) {
    return isbf ? (float)((const bf16*)p)[idx] : ((const float*)p)[idx];
}

__device__ inline unsigned short f2bf(float f) {
    bf16 h = (bf16)f;
    return *(unsigned short*)&h;
}

__device__ inline float bf2f(unsigned short u) {
    bf16 h = *(bf16*)&u;
    return (float)h;
}

// ---------------- K0: dtype detection + c23 zero-init ----------------
__global__ void dtype_detect(const void* __restrict__ seq, int* __restrict__ flag,
                             float* __restrict__ c23) {
    __shared__ int cnt;
    if (threadIdx.x == 0) cnt = 0;
    if (threadIdx.x < 2*C_) c23[threadIdx.x] = 0.f;
    __syncthreads();
    const unsigned short* u = (const unsigned short*)seq;
    int bad = 0;
    for (int i = threadIdx.x; i < 1024; i += 256) {
        unsigned short e = (u[i] >> 7) & 0xFF;
        if (e >= 140) bad++;
    }
    atomicAdd(&cnt, bad);
    __syncthreads();
    if (threadIdx.x == 0) flag[0] = (cnt < 16) ? 1 : 0;   // 1 = bf16 inputs
}

// ---------------- prep: z<8 transposes (32k x 64n), z=8 W_bil->f32, z=9 c23, z=10 W_rel conv ----
struct PrepArgs {
    const void* src[8];
    long off[8];
    int K[8];
    int Ncols[8];
    int Npad[8];
    unsigned short* dst[8];
    const void* W_bil;  float* W_bilF;
    const void* b_f; const void* W_unet; const void* b_unet;
    const void* W_mlp; const void* b_mlp; float* c23;
    const void* W_rel; unsigned short* WBt;
};

union PrepSm {
    float T[32][65];                 // 8320 B
    unsigned short TW[CPAD_][72];    // 16128 B
};

__global__ void prep_kernel(PrepArgs a, const int* __restrict__ dtf) {
    int isbf = dtf[0];
    int z = blockIdx.z;
    __shared__ PrepSm sm;
    int tid = threadIdx.x;
    if (z < 8) {
        int K = a.K[z], Ncols = a.Ncols[z], Npad = a.Npad[z];
        int k0 = blockIdx.x*32, n0 = blockIdx.y*64;
        if (k0 >= K || n0 >= Npad) return;
        const void* src = a.src[z];
        long off = a.off[z];
        unsigned short* dst = a.dst[z];
        // read: 64 consecutive cols per row (coalesced 128/256 B)
        int c64 = tid & 63, r4 = tid >> 6;
        for (int p = 0; p < 8; p++) {
            int r = r4 + p*4;
            int n = n0 + c64;
            sm.T[r][c64] = (n < Ncols) ? ldIn(src, off + (long)(k0+r)*Ncols + n, isbf) : 0.f;
        }
        __syncthreads();
        // write: 32 consecutive k per n (coalesced)
        int cc = tid & 31, n8 = tid >> 5;
        for (int p = 0; p < 8; p++) {
            int nn = n8 + p*8;
            dst[(long)(n0+nn)*K + k0 + cc] = f2bf(sm.T[cc][nn]);
        }
    } else if (z == 8) {
        int lin = blockIdx.y*48 + blockIdx.x;
        int idx = lin*256 + tid;
        if (idx < 291*C_) a.W_bilF[idx] = ldIn(a.W_bil, idx, isbf);
    } else if (z == 9) {
        // c23 partial: 8 blocks x 96 d-rows, coalesced over c, atomic accumulate
        int lin = blockIdx.y*48 + blockIdx.x;
        if (lin >= 8) return;
        int c = tid;
        if (c >= C_) return;
        float s2 = 0.f, s3 = 0.f;
        int d0 = lin*96;
        for (int i = 0; i < 96; i++) {
            int d = d0 + i;
            float bf = ldIn(a.b_f, d, isbf);
            s2 += bf * ldIn(a.W_unet, (long)d*C_ + c, isbf);
            s3 += bf * ldIn(a.W_mlp,  (long)d*C_ + c, isbf);
        }
        if (lin == 0) {
            s2 += ldIn(a.b_unet, c, isbf);
            s3 += ldIn(a.b_mlp,  c, isbf);
        }
        atomicAdd(&a.c23[c], s2);
        atomicAdd(&a.c23[C_ + c], s3);
    } else {
        // W_rel -> WBt TILED: [kstep][c][64] bf16, c padded to 112.
        // Each 64-k step tile is 14336 B CONTIGUOUS -> spreads across all
        // L2/HBM channels (the old [c][k] layout put every step-slice on
        // 1-2 channels: 96KB row stride == 0 mod channel interleave).
        int lin = blockIdx.y*48 + blockIdx.x;
        if (lin >= KTOT_/64) return;
        int k0 = lin * 64;
        for (int idx = tid; idx < 64*97; idx += 256) {
            int kk = idx / 97, c = idx % 97;
            sm.TW[c][kk] = f2bf(ldIn(a.W_rel, (long)(k0+kk)*C_ + c, isbf));
        }
        for (int idx = tid; idx < 15*64; idx += 256) {
            sm.TW[97 + (idx>>6)][idx & 63] = 0;
        }
        __syncthreads();
        unsigned short* tb = a.WBt + (long)lin*TILE_;
        for (int t = 0; t < 4; t++) {
            int idx = tid + t*256;      // < 896 = 112*8
            if (idx < 896) {
                int c = idx >> 3, kc = idx & 7;
                *(uint4*)(tb + idx*8) = *(uint4*)&sm.TW[c][kc*8];
            }
        }
    }
}

// ---------------- gather: bx<768 entatt, else ment ----------------
__global__ void gather_kernel(const void* __restrict__ seq, const void* __restrict__ attn,
                              const int* __restrict__ entity_pos,
                              unsigned short* __restrict__ mentb, float* __restrict__ ent_emb,
                              float* __restrict__ ent_att, const int* __restrict__ dtf) {
    int isbf = dtf[0];
    if (blockIdx.x < 768) {
        int beh = blockIdx.x;
        int h = beh % H_;
        int be = beh / H_;
        int b = be >> 5;
        int pos[M_];
        for (int m = 0; m < M_; m++) pos[m] = entity_pos[be*M_+m] + 1;
        for (int l = threadIdx.x; l < L_; l += 256) {
            float s = 0.f;
            for (int m = 0; m < M_; m++)
                s += ldIn(attn, (((long)(b*H_ + h))*L_ + pos[m])*L_ + l, isbf);
            ent_att[(long)beh*L_ + l] = 0.25f * s;
        }
    } else {
        int be = blockIdx.x - 768;     // 0..63
        int b = be >> 5;
        int pos[M_];
        for (int m = 0; m < M_; m++) pos[m] = entity_pos[be*M_+m] + 1;
        for (int d = threadIdx.x; d < D_; d += 256) {
            float x[M_];
            for (int m = 0; m < M_; m++) {
                x[m] = ldIn(seq, ((long)b*L_ + pos[m])*D_ + d, isbf);
                mentb[((long)be*M_ + m)*D_ + d] = f2bf(x[m]);
            }
            float mx = fmaxf(fmaxf(x[0],x[1]), fmaxf(x[2],x[3]));
            float s = expf(x[0]-mx)+expf(x[1]-mx)+expf(x[2]-mx)+expf(x[3]-mx);
            ent_emb[(long)be*D_ + d] = mx + logf(s);
        }
    }
}

// ---------------- K3: ht_att (bf16) = normalize_L( mean_H(ha*ta) ) ----------------
__global__ void htatt_kernel(const float* __restrict__ ent_att, const int* __restrict__ hts,
                             unsigned short* __restrict__ htb) {
    int bp = blockIdx.x;            // 512 blocks
    int b = bp >> 8;
    int h_e = hts[bp*2+0], t_e = hts[bp*2+1];
    const float* ea_h = ent_att + (long)((b*E_ + h_e)*H_)*L_;
    const float* ea_t = ent_att + (long)((b*E_ + t_e)*H_)*L_;
    __shared__ float red[256];
    float v[2];
    for (int t = 0; t < 2; t++) {
        int l = threadIdx.x + t*256;
        float s = 0.f;
        for (int h = 0; h < H_; h++) s += ea_h[h*L_+l] * ea_t[h*L_+l];
        v[t] = s * (1.0f/H_);
    }
    red[threadIdx.x] = v[0] + v[1];
    __syncthreads();
    for (int off = 128; off > 0; off >>= 1) {
        if (threadIdx.x < off) red[threadIdx.x] += red[threadIdx.x+off];
        __syncthreads();
    }
    float inv = 1.0f / (red[0] + 1e-5f);
    for (int t = 0; t < 2; t++) {
        int l = threadIdx.x + t*256;
        htb[(long)bp*L_ + l] = f2bf(v[t] * inv);
    }
}

// ---------------- catb: hcatb=[hs,rs], tcatb=[ts,rs] in bf16 ----------------
__global__ void catb_kernel(const float* __restrict__ ent_emb, const float* __restrict__ rs,
                            const int* __restrict__ hts,
                            unsigned short* __restrict__ hcatb, unsigned short* __restrict__ tcatb) {
    int n = blockIdx.x;             // 512
    int b = n >> 8;
    int h_e = hts[n*2+0], t_e = hts[n*2+1];
    const float* eh = ent_emb + (long)(b*E_ + h_e)*D_;
    const float* et = ent_emb + (long)(b*E_ + t_e)*D_;
    const float* r  = rs + (long)n*D_;
    for (int k = threadIdx.x; k < D_; k += 256) {
        hcatb[(long)n*1536 + k] = f2bf(eh[k]);
        tcatb[(long)n*1536 + k] = f2bf(et[k]);
        unsigned short rb = f2bf(r[k]);
        hcatb[(long)n*1536 + 768 + k] = rb;
        tcatb[(long)n*1536 + 768 + k] = rb;
    }
}

// ---------------- Generic MFMA GEMM (double-buffered), 32x32 tiles ----------------
struct MfmaJob {
    const unsigned short* A[4];
    const unsigned short* Bt[4];
    const void* bias[4];
    void* C[4];
    int K[4];
    int ldc[4];
    int act[4];
    int obf[4];
};

__global__ void mfma_nt2_kernel(MfmaJob args, const int* __restrict__ dtf) {
    int z = blockIdx.z;
    const unsigned short* A  = args.A[z];
    const unsigned short* Bt = args.Bt[z];
    const void* bias = args.bias[z];
    void* C = args.C[z];
    int K = args.K[z], ldc = args.ldc[z], act = args.act[z], obf = args.obf[z];
    __shared__ unsigned short Al[2][32][72];
    __shared__ unsigned short Btl[2][32][72];
    int m0 = blockIdx.x*32, n0 = blockIdx.y*32;
    int tid = threadIdx.x, wave = tid>>6, lane = tid&63;
    int lm = lane&15, lq = lane>>4;
    int rowg = wave>>1, cgrp = wave&1;   // wave -> (row half, col half)
    int rr = tid >> 3;                // 0..31
    int kc = (tid & 7) * 8;           // col offset in ushorts
    uint4 ra, rb;

    ra = *(const uint4*)(A  + (long)(m0+rr)*K + kc);
    rb = *(const uint4*)(Bt + (long)(n0+rr)*K + kc);
    *(uint4*)&Al[0][rr][kc]  = ra;
    *(uint4*)&Btl[0][rr][kc] = rb;

    int nst = K >> 6;
    f32x4 acc = {};
    for (int ks = 0; ks < nst; ks++) {
        __syncthreads();
        if (ks+1 < nst) {
            int k0 = (ks+1) << 6;
            ra = *(const uint4*)(A  + (long)(m0+rr)*K + k0 + kc);
            rb = *(const uint4*)(Bt + (long)(n0+rr)*K + k0 + kc);
        }
        int cb = ks & 1;
        #pragma unroll
        for (int half = 0; half < 2; half++) {
            bf16x8 af  = *(bf16x8*)&Al[cb][rowg*16+lm][half*32+lq*8];
            bf16x8 bfr = *(bf16x8*)&Btl[cb][cgrp*16+lm][half*32+lq*8];
            acc = __builtin_amdgcn_mfma_f32_16x16x32_bf16(af, bfr, acc, 0, 0, 0);
        }
        if (ks+1 < nst) {
            int nb = (ks+1) & 1;
            *(uint4*)&Al[nb][rr][kc]  = ra;
            *(uint4*)&Btl[nb][rr][kc] = rb;
        }
    }
    int isbf = dtf[0];
    int n = n0 + cgrp*16 + lm;
    float bia = bias ? ldIn(bias, n, isbf) : 0.f;
    #pragma unroll
    for (int r = 0; r < 4; r++) {
        int m = m0 + rowg*16 + lq*4 + r;
        float v = acc[r] + bia;
        if (act == 1) v = tanhf(v);
        if (obf) ((unsigned short*)C)[(long)m*ldc + n] = f2bf(v);
        else     ((float*)C)[(long)m*ldc + n] = v;
    }
}

// ================= r1 via MFMA, on-the-fly A, double-buffered B =================
// v4: WBt is now TILED [kstep][c][64] -> each step stages 14336 contiguous
// bytes (lane i loads tile+16*i), spread across all memory channels. The old
// [c][k] layout serialized every step on 1-2 L2/HBM channels (96KB stride ==
// 0 mod interleave) -> constant ~9000-cycle steps in v0/v2/v3b.
// Epilogue writes the full 512-B partial chunk (acc[3] of cgrp=1 is zero) ->
// no partial-sector RMW.
__global__ __launch_bounds__(256, 3)
void r1_mfma_kernel(const float* __restrict__ hz, const float* __restrict__ tz,
                    const unsigned short* __restrict__ WBt,
                    float* __restrict__ partial) {
    __shared__ unsigned short Btl[2][CPAD_][72];
    __shared__ float hzL[32][17];
    int kz = blockIdx.x;
    int n0 = blockIdx.y * 32;
    int kbase = kz * KCHUNK_;
    int gk0 = kz * (KCHUNK_/64);     // global k-step base = kz*16
    int gi0 = kbase >> 6;            // hz col base = kz*16
    int g0 = kbase >> 12;            // tz group, fixed for the whole chunk
    int tid = threadIdx.x;
    int wave = tid >> 6, lane = tid & 63;
    int lm = lane & 15, lq = lane >> 4;
    int rowg = wave >> 1;            // 0..1  (16-row group)
    int cgrp = wave & 1;             // 0 -> c-tiles 0..3, 1 -> c-tiles 4..6
    int nrow = n0 + rowg*16 + lm;

    // hz tile 32 rows x 16 cols -> LDS (512 elems, 2 per thread)
    {
        int r = tid >> 3, q = (tid & 7) * 2;
        float2 v = *(const float2*)(hz + (long)(n0 + r)*EMB_ + gi0 + q);
        hzL[r][q] = v.x; hzL[r][q+1] = v.y;
    }
    // tz fragment for this row, f32 (16 regs): cols g0*64 + half*32 + lq*8 + e
    f32x8 t0, t1;
    {
        const float* tp = tz + (long)nrow*EMB_ + g0*64;
        float4 a = *(const float4*)(tp + lq*8);
        float4 b = *(const float4*)(tp + lq*8 + 4);
        float4 c = *(const float4*)(tp + 32 + lq*8);
        float4 d = *(const float4*)(tp + 32 + lq*8 + 4);
        t0[0]=a.x; t0[1]=a.y; t0[2]=a.z; t0[3]=a.w;
        t0[4]=b.x; t0[5]=b.y; t0[6]=b.z; t0[7]=b.w;
        t1[0]=c.x; t1[1]=c.y; t1[2]=c.z; t1[3]=c.w;
        t1[4]=d.x; t1[5]=d.y; t1[6]=d.z; t1[7]=d.w;
    }

    // prologue: stage B tile for ks=0 (contiguous 14336 B)
    {
        const unsigned short* tb = WBt + (long)gk0*TILE_;
        #pragma unroll
        for (int t = 0; t < 4; t++) {
            int idx = tid + t*256;
            if (idx < 896) {
                *(uint4*)&Btl[0][idx>>3][(idx&7)*8] = *(const uint4*)(tb + idx*8);
            }
        }
    }

    f32x4 acc[4] = {};
    int nct = 4 - cgrp;             // 4 or 3 c-tiles per wave (MFMA only)
    uint4 rb[4];
    #pragma unroll 2
    for (int ks = 0; ks < KCHUNK_/64; ks++) {
        __syncthreads();
        if (ks+1 < KCHUNK_/64) {
            const unsigned short* tb = WBt + (long)(gk0+ks+1)*TILE_;
            #pragma unroll
            for (int t = 0; t < 4; t++) {
                int idx = tid + t*256;
                if (idx < 896) {
                    rb[t] = *(const uint4*)(tb + idx*8);
                }
            }
        }
        int cb = ks & 1;
        float hvk = hzL[rowg*16 + lm][ks];
        // A-frag: oa[h] = bf16( tz[h] * hv[ks] )  (2 VALU/elem: mul + cvt)
        unsigned short oa0[8], oa1[8];
        #pragma unroll
        for (int e = 0; e < 8; e++) {
            oa0[e] = f2bf(t0[e] * hvk);
            oa1[e] = f2bf(t1[e] * hvk);
        }
        #pragma unroll
        for (int h = 0; h < 2; h++) {
            bf16x8 afrag = (h == 0) ? *(bf16x8*)oa0 : *(bf16x8*)oa1;
            #pragma unroll
            for (int ct = 0; ct < 4; ct++) {
                if (ct < nct) {
                    bf16x8 bfrag = *(bf16x8*)&Btl[cb][(cgrp*4+ct)*16 + lm][h*32 + lq*8];
                    acc[ct] = __builtin_amdgcn_mfma_f32_16x16x32_bf16(afrag, bfrag, acc[ct], 0, 0, 0);
                }
            }
        }
        if (ks+1 < KCHUNK_/64) {
            int nb = (ks+1) & 1;
            #pragma unroll
            for (int t = 0; t < 4; t++) {
                int idx = tid + t*256;
                if (idx < 896) {
                    *(uint4*)&Btl[nb][idx>>3][(idx&7)*8] = rb[t];
                }
            }
        }
    }
    // epilogue: write ALL 4 c-tiles per wave (c 0..127) so every 512-B chunk
    // is fully written -> no partial-sector RMW. acc[3] of cgrp=1 is zero.
    #pragma unroll
    for (int ct = 0; ct < 4; ct++) {
        int c = (cgrp*4 + ct)*16 + lm;
        #pragma unroll
        for (int r = 0; r < 4; r++) {
            int nl = rowg*16 + lq*4 + r;
            partial[((long)(n0+nl)*KSPLIT_ + kz)*PSTR_ + c] = acc[ct][r];
        }
    }
}

// ---------------- fused: r1 streaming reduce + r2/r3 LSE + final projection ----------------
__global__ void r23out_kernel(const float* __restrict__ partial, const void* __restrict__ b_rel,
                              const float* __restrict__ mu, const float* __restrict__ c23,
                              const int* __restrict__ hts, const int* __restrict__ mention_idx,
                              const float* __restrict__ W_bilF, const void* __restrict__ b_bil,
                              void* __restrict__ out, const int* __restrict__ dtf) {
    int bp = blockIdx.x;
    int b = bp >> 8;
    int c = threadIdx.x;
    int isbf = dtf[0];
    __shared__ float row[292];
    if (c < C_) {
        const float* pr = partial + (long)bp*KSPLIT_*PSTR_;
        float r1v = 0.f;
        #pragma unroll 8
        for (int kz = 0; kz < KSPLIT_; kz++)
            r1v += pr[kz*PSTR_ + c];
        r1v += ldIn(b_rel, c, isbf);
        int h_e = hts[bp*2+0], t_e = hts[bp*2+1];
        const float* mu2h = mu;
        const float* mu2t = mu + 32768;
        const float* mu3h = mu + 65536;
        const float* mu3t = mu + 98304;
        float ah2[4], at2[4], ah3[4], at3[4];
        for (int m = 0; m < 4; m++) {
            int emh = mention_idx[(b*E_ + h_e)*M_ + m];
            int emt = mention_idx[(b*E_ + t_e)*M_ + m];
            ah2[m] = mu2h[(long)(b*128 + emh)*128 + c];
            ah3[m] = mu3h[(long)(b*128 + emh)*128 + c];
            at2[m] = mu2t[(long)(b*128 + emt)*128 + c];
            at3[m] = mu3t[(long)(b*128 + emt)*128 + c];
        }
        float c2 = c23[c], c3 = c23[C_ + c];
        float v2[16], v3[16];
        int q = 0;
        for (int i = 0; i < 4; i++) {
            for (int j = 0; j < 4; j++, q++) {
                float x2 = ah2[i] + at2[j] + c2;
                v2[q] = tanhf(x2);
                float x3 = ah3[i] + at3[j] + c3;
                float t = tanhf(0.7978845608028654f * (x3 + 0.044715f*x3*x3*x3));
                v3[q] = 0.5f * x3 * (1.0f + t);
            }
        }
        float m2 = v2[0], m3 = v3[0];
        for (q = 1; q < 16; q++) { m2 = fmaxf(m2, v2[q]); m3 = fmaxf(m3, v3[q]); }
        float s2 = 0.f, s3 = 0.f;
        for (q = 0; q < 16; q++) { s2 += expf(v2[q]-m2); s3 += expf(v3[q]-m3); }
        row[c]        = r1v;
        row[C_ + c]   = m2 + logf(s2);
        row[2*C_ + c] = m3 + logf(s3);
    }
    __syncthreads();
    if (c >= C_) return;
    float a0 = 0.f, a1 = 0.f, a2 = 0.f, a3 = 0.f;
    #pragma unroll 4
    for (int k = 0; k < 288; k += 4) {
        a0 += row[k+0] * W_bilF[(k+0)*C_ + c];
        a1 += row[k+1] * W_bilF[(k+1)*C_ + c];
        a2 += row[k+2] * W_bilF[(k+2)*C_ + c];
        a3 += row[k+3] * W_bilF[(k+3)*C_ + c];
    }
    a0 += row[288] * W_bilF[288*C_ + c];
    a1 += row[289] * W_bilF[289*C_ + c];
    a2 += row[290] * W_bilF[290*C_ + c];
    float v = a0 + a1 + a2 + a3 + ldIn(b_bil, c, isbf);
    if (isbf) ((bf16*)out)[(long)bp*C_ + c] = (bf16)v;
    else      ((float*)out)[(long)bp*C_ + c] = v;
}

extern "C" void kernel_launch(void* const* d_in, const int* in_sizes, int n_in,
                              void* d_out, int out_size, void* d_ws, size_t ws_size,
                              hipStream_t stream) {
    const void* seq        = d_in[0];
    const void* attn       = d_in[1];
    const int*  entity_pos = (const int*)d_in[2];
    const int*  hts        = (const int*)d_in[3];
    const int*  mention_idx= (const int*)d_in[4];
    const void* W_head     = d_in[5];
    const void* b_head     = d_in[6];
    const void* W_tail     = d_in[7];
    const void* b_tail     = d_in[8];
    const void* W_rel      = d_in[9];
    const void* b_rel      = d_in[10];
    const void* W_fh       = d_in[11];
    const void* W_ft       = d_in[12];
    const void* b_f        = d_in[13];
    const void* W_unet     = d_in[14];
    const void* b_unet     = d_in[15];
    const void* W_mlp      = d_in[16];
    const void* b_mlp      = d_in[17];
    const void* W_bil      = d_in[18];
    const void* b_bil      = d_in[19];

    float* w = (float*)d_ws;
    int*   dtf      = (int*)w;                               // 64
    unsigned short* mentb = (unsigned short*)(w + 64);       // 98304 fl
    float* ent_emb  = w + 98368;                             // 49152
    float* ent_att  = w + 147520;                            // 393216
    unsigned short* htb = (unsigned short*)(w + 540736);     // 131072 fl
    float* rs       = w + 671808;                            // 393216
    float* hz       = w + 1065024;                           // 393216
    float* tz       = w + 1458240;                           // 393216
    float* mu       = w + 1851456;                           // 131072
    float* c23      = w + 1982528;                           // 256
    unsigned short* seqT  = (unsigned short*)(w + 1982784);  // 393216 fl
    unsigned short* WhT   = (unsigned short*)(w + 2376000);  // 589824 fl
    unsigned short* WtT   = (unsigned short*)(w + 2965824);  // 589824 fl
    unsigned short* WfhT  = (unsigned short*)(w + 3555648);  // 294912 fl
    unsigned short* WftT  = (unsigned short*)(w + 3850560);  // 294912 fl
    unsigned short* WunetT= (unsigned short*)(w + 4145472);  // 49152 fl
    unsigned short* WmlpT = (unsigned short*)(w + 4194624);  // 49152 fl
    unsigned short* Tbh   = (unsigned short*)(w + 4243776);  // 98304 fl
    unsigned short* Tbt   = (unsigned short*)(w + 4342080);  // 98304 fl
    unsigned short* hcatb = (unsigned short*)(w + 4440384);  // 393216 fl
    unsigned short* tcatb = (unsigned short*)(w + 4833600);  // 393216 fl
    unsigned short* WBt   = (unsigned short*)(w + 5226816);  // 2752512 fl (tiled: 768*7168 ushorts, exact fit)
    float* partial  = w + 7979328;                           // 3670016 fl (used: 512*48*128 = 3145728)
    float* W_bilF   = w + 11649344;                          // 28227 fl

    // 0. dtype detection + c23 init
    dtype_detect<<<1, 256, 0, stream>>>(seq, dtf, c23);
    // 1. prep: transposes + W_bilF + c23 + W_rel conv
    {
        PrepArgs a = {};
        const void* srcs[8] = {W_head, W_tail, W_fh, W_ft, W_unet, W_mlp, seq, seq};
        long offs[8]   = {0,0,0,0,0,0,0,393216};
        int Ks[8]      = {1536,1536,768,768,768,768,512,512};
        int Ncols8[8]  = {768,768,768,768,97,97,768,768};
        int Npads[8]   = {768,768,768,768,128,128,768,768};
        unsigned short* dsts[8] = {WhT, WtT, WfhT, WftT, WunetT, WmlpT, seqT, seqT+393216};
        for (int z = 0; z < 8; z++) {
            a.src[z]=srcs[z]; a.off[z]=offs[z]; a.K[z]=Ks[z];
            a.Ncols[z]=Ncols8[z]; a.Npad[z]=Npads[z]; a.dst[z]=dsts[z];
        }
        a.W_bil = W_bil; a.W_bilF = W_bilF;
        a.b_f = b_f; a.W_unet = W_unet; a.b_unet = b_unet;
        a.W_mlp = W_mlp; a.b_mlp = b_mlp; a.c23 = c23;
        a.W_rel = W_rel; a.WBt = WBt;
        prep_kernel<<<dim3(48, 16, 11), 256, 0, stream>>>(a, dtf);
    }
    // 2. gather: entatt + ment
    gather_kernel<<<768 + 64, 256, 0, stream>>>(seq, attn, entity_pos, mentb, ent_emb, ent_att, dtf);
    // 3. ht attention (normalized, bf16)
    htatt_kernel<<<N_, 256, 0, stream>>>(ent_att, hts, htb);
    // 4. gemmA: rs (z=0,1) + T_{h,t} (z=2,3)  [32x32 tiles]
    {
        MfmaJob ga = {};
        for (int z = 0; z < 2; z++) {
            ga.A[z] = htb + (long)z*256*512; ga.Bt[z] = seqT + (long)z*393216;
            ga.bias[z] = nullptr; ga.C[z] = rs + (long)z*256*768;
            ga.K[z] = 512; ga.ldc[z] = 768; ga.act[z] = 0; ga.obf[z] = 0;
        }
        ga.A[2] = mentb; ga.Bt[2] = WfhT; ga.bias[2] = nullptr; ga.C[2] = Tbh;
        ga.K[2] = 768; ga.ldc[2] = 768; ga.act[2] = 0; ga.obf[2] = 1;
        ga.A[3] = mentb; ga.Bt[3] = WftT; ga.bias[3] = nullptr; ga.C[3] = Tbt;
        ga.K[3] = 768; ga.ldc[3] = 768; ga.act[3] = 0; ga.obf[3] = 1;
        mfma_nt2_kernel<<<dim3(8, 24, 4), 256, 0, stream>>>(ga, dtf);
    }
    // 5. concatenated inputs (bf16)
    catb_kernel<<<N_, 256, 0, stream>>>(ent_emb, rs, hts, hcatb, tcatb);
    // 6. gemmB: hz/tz = tanh(cat @ W + b)
    {
        MfmaJob ga = {};
        ga.A[0] = hcatb; ga.Bt[0] = WhT; ga.bias[0] = b_head; ga.C[0] = hz;
        ga.A[1] = tcatb; ga.Bt[1] = WtT; ga.bias[1] = b_tail; ga.C[1] = tz;
        for (int z = 0; z < 2; z++) { ga.K[z] = 1536; ga.ldc[z] = 768; ga.act[z] = 1; ga.obf[z] = 0; }
        mfma_nt2_kernel<<<dim3(16, 24, 2), 256, 0, stream>>>(ga, dtf);
    }
    // 7. gemmC: mu_q = T @ W_{unet,mlp}
    {
        MfmaJob ga = {};
        const unsigned short* As[4] = {Tbh, Tbt, Tbh, Tbt};
        const unsigned short* Bs[4] = {WunetT, WunetT, WmlpT, WmlpT};
        for (int q = 0; q < 4; q++) {
            ga.A[q] = As[q]; ga.Bt[q] = Bs[q]; ga.bias[q] = nullptr;
            ga.C[q] = mu + q*32768;
            ga.K[q] = 768; ga.ldc[q] = 128; ga.act[q] = 0; ga.obf[q] = 0;
        }
        mfma_nt2_kernel<<<dim3(8, 4, 4), 256, 0, stream>>>(ga, dtf);
    }
    // 8. r1 partials via MFMA (kz-fastest grid for XCD slice affinity; 32-row n-tiles)
    r1_mfma_kernel<<<dim3(KSPLIT_, 16), 256, 0, stream>>>(hz, tz, WBt, partial);
    // 9. fused reduce + r2/r3 + final projection
    r23out_kernel<<<N_, 128, 0, stream>>>(partial, b_rel, mu, c23, hts, mention_idx,
                                          W_bilF, b_bil, d_out, dtf);
}

// Round 6
// 258.791 us; speedup vs baseline: 1.0569x; 1.0452x over previous
//
#include <hip/hip_runtime.h>
#include <hip/hip_bf16.h>

// Problem constants
#define B_  2
#define L_  512
#define D_  768
#define H_  12
#define E_  32
#define M_  4
#define P_  256
#define EMB_ 768
#define BS_ 64
#define C_  97
#define N_  (B_*P_)   // 512

#define KTOT_    49152      // EMB*BS
#define CPAD_    112        // 97 padded to 7*16
#define KSPLIT_  48
#define KCHUNK_  (KTOT_/KSPLIT_)   // 1024, 16 ks-steps of 64; divides 4096 -> no group crossing
#define PSTR_    128        // partial chunk stride (floats): 512 B, cache-line exclusive
#define TILE_    (CPAD_*64) // 7168 ushorts = 14336 B per k-step tile of WBt

typedef __hip_bfloat16 bf16;
typedef __attribute__((ext_vector_type(8))) short bf16x8;
typedef __attribute__((ext_vector_type(4))) float f32x4;
typedef __attribute__((ext_vector_type(8))) float f32x8;

__device__ inline float ldIn(const void* p, long idx, int isbf) {
    return isbf ? (float)((const bf16*)p)[idx] : ((const float*)p)[idx];
}

__device__ inline unsigned short f2bf(float f) {
    bf16 h = (bf16)f;
    return *(unsigned short*)&h;
}

__device__ inline float bf2f(unsigned short u) {
    bf16 h = *(bf16*)&u;
    return (float)h;
}

// ---------------- K0: dtype detection + c23 zero-init ----------------
__global__ void dtype_detect(const void* __restrict__ seq, int* __restrict__ flag,
                             float* __restrict__ c23) {
    __shared__ int cnt;
    if (threadIdx.x == 0) cnt = 0;
    if (threadIdx.x < 2*C_) c23[threadIdx.x] = 0.f;
    __syncthreads();
    const unsigned short* u = (const unsigned short*)seq;
    int bad = 0;
    for (int i = threadIdx.x; i < 1024; i += 256) {
        unsigned short e = (u[i] >> 7) & 0xFF;
        if (e >= 140) bad++;
    }
    atomicAdd(&cnt, bad);
    __syncthreads();
    if (threadIdx.x == 0) flag[0] = (cnt < 16) ? 1 : 0;   // 1 = bf16 inputs
}

// ---------------- prep: z<8 transposes (32k x 64n), z=8 W_bil->f32, z=9 c23, z=10 W_rel conv ----
struct PrepArgs {
    const void* src[8];
    long off[8];
    int K[8];
    int Ncols[8];
    int Npad[8];
    unsigned short* dst[8];
    const void* W_bil;  float* W_bilF;
    const void* b_f; const void* W_unet; const void* b_unet;
    const void* W_mlp; const void* b_mlp; float* c23;
    const void* W_rel; unsigned short* WBt;
};

union PrepSm {
    float T[32][65];                 // 8320 B
    unsigned short TW[CPAD_][72];    // 16128 B
};

__global__ void prep_kernel(PrepArgs a, const int* __restrict__ dtf) {
    int isbf = dtf[0];
    int z = blockIdx.z;
    __shared__ PrepSm sm;
    int tid = threadIdx.x;
    if (z < 8) {
        int K = a.K[z], Ncols = a.Ncols[z], Npad = a.Npad[z];
        int k0 = blockIdx.x*32, n0 = blockIdx.y*64;
        if (k0 >= K || n0 >= Npad) return;
        const void* src = a.src[z];
        long off = a.off[z];
        unsigned short* dst = a.dst[z];
        // read: 64 consecutive cols per row (coalesced 128/256 B)
        int c64 = tid & 63, r4 = tid >> 6;
        for (int p = 0; p < 8; p++) {
            int r = r4 + p*4;
            int n = n0 + c64;
            sm.T[r][c64] = (n < Ncols) ? ldIn(src, off + (long)(k0+r)*Ncols + n, isbf) : 0.f;
        }
        __syncthreads();
        // write: 32 consecutive k per n (coalesced)
        int cc = tid & 31, n8 = tid >> 5;
        for (int p = 0; p < 8; p++) {
            int nn = n8 + p*8;
            dst[(long)(n0+nn)*K + k0 + cc] = f2bf(sm.T[cc][nn]);
        }
    } else if (z == 8) {
        int lin = blockIdx.y*48 + blockIdx.x;
        int idx = lin*256 + tid;
        if (idx < 291*C_) a.W_bilF[idx] = ldIn(a.W_bil, idx, isbf);
    } else if (z == 9) {
        // c23 partial: 8 blocks x 96 d-rows, coalesced over c, atomic accumulate
        int lin = blockIdx.y*48 + blockIdx.x;
        if (lin >= 8) return;
        int c = tid;
        if (c >= C_) return;
        float s2 = 0.f, s3 = 0.f;
        int d0 = lin*96;
        for (int i = 0; i < 96; i++) {
            int d = d0 + i;
            float bf = ldIn(a.b_f, d, isbf);
            s2 += bf * ldIn(a.W_unet, (long)d*C_ + c, isbf);
            s3 += bf * ldIn(a.W_mlp,  (long)d*C_ + c, isbf);
        }
        if (lin == 0) {
            s2 += ldIn(a.b_unet, c, isbf);
            s3 += ldIn(a.b_mlp,  c, isbf);
        }
        atomicAdd(&a.c23[c], s2);
        atomicAdd(&a.c23[C_ + c], s3);
    } else {
        // W_rel -> WBt TILED: [kstep][c][64] bf16, c padded to 112.
        // Each 64-k step tile is 14336 B contiguous.
        int lin = blockIdx.y*48 + blockIdx.x;
        if (lin >= KTOT_/64) return;
        int k0 = lin * 64;
        for (int idx = tid; idx < 64*97; idx += 256) {
            int kk = idx / 97, c = idx % 97;
            sm.TW[c][kk] = f2bf(ldIn(a.W_rel, (long)(k0+kk)*C_ + c, isbf));
        }
        for (int idx = tid; idx < 15*64; idx += 256) {
            sm.TW[97 + (idx>>6)][idx & 63] = 0;
        }
        __syncthreads();
        unsigned short* tb = a.WBt + (long)lin*TILE_;
        for (int t = 0; t < 4; t++) {
            int idx = tid + t*256;      // < 896 = 112*8
            if (idx < 896) {
                int c = idx >> 3, kc = idx & 7;
                *(uint4*)(tb + idx*8) = *(uint4*)&sm.TW[c][kc*8];
            }
        }
    }
}

// ---------------- gather: bx<768 entatt, else ment ----------------
__global__ void gather_kernel(const void* __restrict__ seq, const void* __restrict__ attn,
                              const int* __restrict__ entity_pos,
                              unsigned short* __restrict__ mentb, float* __restrict__ ent_emb,
                              float* __restrict__ ent_att, const int* __restrict__ dtf) {
    int isbf = dtf[0];
    if (blockIdx.x < 768) {
        int beh = blockIdx.x;
        int h = beh % H_;
        int be = beh / H_;
        int b = be >> 5;
        int pos[M_];
        for (int m = 0; m < M_; m++) pos[m] = entity_pos[be*M_+m] + 1;
        for (int l = threadIdx.x; l < L_; l += 256) {
            float s = 0.f;
            for (int m = 0; m < M_; m++)
                s += ldIn(attn, (((long)(b*H_ + h))*L_ + pos[m])*L_ + l, isbf);
            ent_att[(long)beh*L_ + l] = 0.25f * s;
        }
    } else {
        int be = blockIdx.x - 768;     // 0..63
        int b = be >> 5;
        int pos[M_];
        for (int m = 0; m < M_; m++) pos[m] = entity_pos[be*M_+m] + 1;
        for (int d = threadIdx.x; d < D_; d += 256) {
            float x[M_];
            for (int m = 0; m < M_; m++) {
                x[m] = ldIn(seq, ((long)b*L_ + pos[m])*D_ + d, isbf);
                mentb[((long)be*M_ + m)*D_ + d] = f2bf(x[m]);
            }
            float mx = fmaxf(fmaxf(x[0],x[1]), fmaxf(x[2],x[3]));
            float s = expf(x[0]-mx)+expf(x[1]-mx)+expf(x[2]-mx)+expf(x[3]-mx);
            ent_emb[(long)be*D_ + d] = mx + logf(s);
        }
    }
}

// ---------------- K3: ht_att (bf16) = normalize_L( mean_H(ha*ta) ) ----------------
__global__ void htatt_kernel(const float* __restrict__ ent_att, const int* __restrict__ hts,
                             unsigned short* __restrict__ htb) {
    int bp = blockIdx.x;            // 512 blocks
    int b = bp >> 8;
    int h_e = hts[bp*2+0], t_e = hts[bp*2+1];
    const float* ea_h = ent_att + (long)((b*E_ + h_e)*H_)*L_;
    const float* ea_t = ent_att + (long)((b*E_ + t_e)*H_)*L_;
    __shared__ float red[256];
    float v[2];
    for (int t = 0; t < 2; t++) {
        int l = threadIdx.x + t*256;
        float s = 0.f;
        for (int h = 0; h < H_; h++) s += ea_h[h*L_+l] * ea_t[h*L_+l];
        v[t] = s * (1.0f/H_);
    }
    red[threadIdx.x] = v[0] + v[1];
    __syncthreads();
    for (int off = 128; off > 0; off >>= 1) {
        if (threadIdx.x < off) red[threadIdx.x] += red[threadIdx.x+off];
        __syncthreads();
    }
    float inv = 1.0f / (red[0] + 1e-5f);
    for (int t = 0; t < 2; t++) {
        int l = threadIdx.x + t*256;
        htb[(long)bp*L_ + l] = f2bf(v[t] * inv);
    }
}

// ---------------- catb: hcatb=[hs,rs], tcatb=[ts,rs] in bf16 ----------------
__global__ void catb_kernel(const float* __restrict__ ent_emb, const float* __restrict__ rs,
                            const int* __restrict__ hts,
                            unsigned short* __restrict__ hcatb, unsigned short* __restrict__ tcatb) {
    int n = blockIdx.x;             // 512
    int b = n >> 8;
    int h_e = hts[n*2+0], t_e = hts[n*2+1];
    const float* eh = ent_emb + (long)(b*E_ + h_e)*D_;
    const float* et = ent_emb + (long)(b*E_ + t_e)*D_;
    const float* r  = rs + (long)n*D_;
    for (int k = threadIdx.x; k < D_; k += 256) {
        hcatb[(long)n*1536 + k] = f2bf(eh[k]);
        tcatb[(long)n*1536 + k] = f2bf(et[k]);
        unsigned short rb = f2bf(r[k]);
        hcatb[(long)n*1536 + 768 + k] = rb;
        tcatb[(long)n*1536 + 768 + k] = rb;
    }
}

// ---------------- Generic MFMA GEMM (double-buffered), 32x32 tiles ----------------
struct MfmaJob {
    const unsigned short* A[4];
    const unsigned short* Bt[4];
    const void* bias[4];
    void* C[4];
    int K[4];
    int ldc[4];
    int act[4];
    int obf[4];
};

__global__ void mfma_nt2_kernel(MfmaJob args, const int* __restrict__ dtf) {
    int z = blockIdx.z;
    const unsigned short* A  = args.A[z];
    const unsigned short* Bt = args.Bt[z];
    const void* bias = args.bias[z];
    void* C = args.C[z];
    int K = args.K[z], ldc = args.ldc[z], act = args.act[z], obf = args.obf[z];
    __shared__ unsigned short Al[2][32][72];
    __shared__ unsigned short Btl[2][32][72];
    int m0 = blockIdx.x*32, n0 = blockIdx.y*32;
    int tid = threadIdx.x, wave = tid>>6, lane = tid&63;
    int lm = lane&15, lq = lane>>4;
    int rowg = wave>>1, cgrp = wave&1;   // wave -> (row half, col half)
    int rr = tid >> 3;                // 0..31
    int kc = (tid & 7) * 8;           // col offset in ushorts
    uint4 ra, rb;

    ra = *(const uint4*)(A  + (long)(m0+rr)*K + kc);
    rb = *(const uint4*)(Bt + (long)(n0+rr)*K + kc);
    *(uint4*)&Al[0][rr][kc]  = ra;
    *(uint4*)&Btl[0][rr][kc] = rb;

    int nst = K >> 6;
    f32x4 acc = {};
    for (int ks = 0; ks < nst; ks++) {
        __syncthreads();
        if (ks+1 < nst) {
            int k0 = (ks+1) << 6;
            ra = *(const uint4*)(A  + (long)(m0+rr)*K + k0 + kc);
            rb = *(const uint4*)(Bt + (long)(n0+rr)*K + k0 + kc);
        }
        int cb = ks & 1;
        #pragma unroll
        for (int half = 0; half < 2; half++) {
            bf16x8 af  = *(bf16x8*)&Al[cb][rowg*16+lm][half*32+lq*8];
            bf16x8 bfr = *(bf16x8*)&Btl[cb][cgrp*16+lm][half*32+lq*8];
            acc = __builtin_amdgcn_mfma_f32_16x16x32_bf16(af, bfr, acc, 0, 0, 0);
        }
        if (ks+1 < nst) {
            int nb = (ks+1) & 1;
            *(uint4*)&Al[nb][rr][kc]  = ra;
            *(uint4*)&Btl[nb][rr][kc] = rb;
        }
    }
    int isbf = dtf[0];
    int n = n0 + cgrp*16 + lm;
    float bia = bias ? ldIn(bias, n, isbf) : 0.f;
    #pragma unroll
    for (int r = 0; r < 4; r++) {
        int m = m0 + rowg*16 + lq*4 + r;
        float v = acc[r] + bia;
        if (act == 1) v = tanhf(v);
        if (obf) ((unsigned short*)C)[(long)m*ldc + n] = f2bf(v);
        else     ((float*)C)[(long)m*ldc + n] = v;
    }
}

// ================= r1 via MFMA =================
// v5: deep-compute-per-tile. Each block: one kz chunk (16 W-tiles of 14 KB) x
// 128 n-rows. Grid (48,4)=192 blocks, ~1 block/CU. Per W-tile the block now
// runs 4 n-chunks x 28 MFMA (~500 cyc/SIMD) instead of 14 MFMA total -- the
// tile-load latency (the constant ~8.6k-cyc/step disease of v0..v4, which
// survived every layout change) is amortized 8x, and tile sharers drop 16->4.
// tz fragments live in REGISTERS (hoisted once: group g0 fixed per chunk);
// B-fragments read from LDS once per tile, reused across all 4 n-chunks;
// hz in a small LDS tile. Double-buffered tile staging as before.
__global__ __launch_bounds__(256, 1)
void r1_mfma_kernel(const float* __restrict__ hz, const float* __restrict__ tz,
                    const unsigned short* __restrict__ WBt,
                    float* __restrict__ partial) {
    __shared__ unsigned short Btl[2][CPAD_][72];   // 32256 B
    __shared__ float hzL[128][17];                 // 8704 B
    int kz = blockIdx.x;
    int nb0 = blockIdx.y * 128;
    int kbase = kz * KCHUNK_;
    int gk0 = kz * (KCHUNK_/64);     // global k-step base = kz*16
    int gi0 = kbase >> 6;            // hz col base = kz*16
    int g0 = kbase >> 12;            // tz group, fixed for the whole chunk
    int tid = threadIdx.x;
    int wave = tid >> 6, lane = tid & 63;
    int lm = lane & 15, lq = lane >> 4;
    int rowg = wave >> 1;            // 0..1  (16-row group within 32-row n-chunk)
    int cgrp = wave & 1;             // 0 -> c-tiles 0..3, 1 -> c-tiles 4..6
    int nct = 4 - cgrp;

    // hz tile 128 rows x 16 cols -> LDS (2048 elems, 8 per thread)
    {
        int r = tid >> 1, q = (tid & 1) * 8;
        const float* hp = hz + (long)(nb0 + r)*EMB_ + gi0 + q;
        float4 v0 = *(const float4*)hp;
        float4 v1 = *(const float4*)(hp + 4);
        hzL[r][q+0]=v0.x; hzL[r][q+1]=v0.y; hzL[r][q+2]=v0.z; hzL[r][q+3]=v0.w;
        hzL[r][q+4]=v1.x; hzL[r][q+5]=v1.y; hzL[r][q+6]=v1.z; hzL[r][q+7]=v1.w;
    }
    // tz fragments for this lane's 4 rows, f32 in registers (64 VGPR)
    f32x8 ta[4], tb[4];
    #pragma unroll
    for (int nc = 0; nc < 4; nc++) {
        const float* tp = tz + (long)(nb0 + nc*32 + rowg*16 + lm)*EMB_ + g0*64;
        float4 x0 = *(const float4*)(tp + lq*8);
        float4 y0 = *(const float4*)(tp + lq*8 + 4);
        float4 x1 = *(const float4*)(tp + 32 + lq*8);
        float4 y1 = *(const float4*)(tp + 32 + lq*8 + 4);
        ta[nc][0]=x0.x; ta[nc][1]=x0.y; ta[nc][2]=x0.z; ta[nc][3]=x0.w;
        ta[nc][4]=y0.x; ta[nc][5]=y0.y; ta[nc][6]=y0.z; ta[nc][7]=y0.w;
        tb[nc][0]=x1.x; tb[nc][1]=x1.y; tb[nc][2]=x1.z; tb[nc][3]=x1.w;
        tb[nc][4]=y1.x; tb[nc][5]=y1.y; tb[nc][6]=y1.z; tb[nc][7]=y1.w;
    }

    // prologue: stage W tile for ks=0 (contiguous 14336 B)
    {
        const unsigned short* tbp = WBt + (long)gk0*TILE_;
        #pragma unroll
        for (int t = 0; t < 4; t++) {
            int idx = tid + t*256;
            if (idx < 896) {
                *(uint4*)&Btl[0][idx>>3][(idx&7)*8] = *(const uint4*)(tbp + idx*8);
            }
        }
    }

    f32x4 acc[4][4] = {};
    uint4 rb[4];
    #pragma unroll 2
    for (int ks = 0; ks < KCHUNK_/64; ks++) {
        __syncthreads();
        if (ks+1 < KCHUNK_/64) {
            const unsigned short* tbp = WBt + (long)(gk0+ks+1)*TILE_;
            #pragma unroll
            for (int t = 0; t < 4; t++) {
                int idx = tid + t*256;
                if (idx < 896) {
                    rb[t] = *(const uint4*)(tbp + idx*8);
                }
            }
        }
        int cb = ks & 1;
        // B-frags for this wave's c-tiles, both halves: read once per tile
        bf16x8 bf0[4], bf1[4];
        #pragma unroll
        for (int ct = 0; ct < 4; ct++) {
            if (ct < nct) {
                bf0[ct] = *(bf16x8*)&Btl[cb][(cgrp*4+ct)*16 + lm][lq*8];
                bf1[ct] = *(bf16x8*)&Btl[cb][(cgrp*4+ct)*16 + lm][32 + lq*8];
            }
        }
        #pragma unroll
        for (int nc = 0; nc < 4; nc++) {
            float hvk = hzL[nc*32 + rowg*16 + lm][ks];
            unsigned short oa0[8], oa1[8];
            #pragma unroll
            for (int e = 0; e < 8; e++) {
                oa0[e] = f2bf(ta[nc][e] * hvk);
                oa1[e] = f2bf(tb[nc][e] * hvk);
            }
            bf16x8 a0 = *(bf16x8*)oa0;
            bf16x8 a1 = *(bf16x8*)oa1;
            #pragma unroll
            for (int ct = 0; ct < 4; ct++) {
                if (ct < nct) {
                    acc[nc][ct] = __builtin_amdgcn_mfma_f32_16x16x32_bf16(a0, bf0[ct], acc[nc][ct], 0, 0, 0);
                    acc[nc][ct] = __builtin_amdgcn_mfma_f32_16x16x32_bf16(a1, bf1[ct], acc[nc][ct], 0, 0, 0);
                }
            }
        }
        if (ks+1 < KCHUNK_/64) {
            int nb = (ks+1) & 1;
            #pragma unroll
            for (int t = 0; t < 4; t++) {
                int idx = tid + t*256;
                if (idx < 896) {
                    *(uint4*)&Btl[nb][idx>>3][(idx&7)*8] = rb[t];
                }
            }
        }
    }
    // epilogue: write ALL 4 c-tiles per wave (c 0..127) so every 512-B chunk
    // is fully written -> no partial-sector RMW. acc[nc][3] of cgrp=1 is zero.
    #pragma unroll
    for (int nc = 0; nc < 4; nc++) {
        #pragma unroll
        for (int ct = 0; ct < 4; ct++) {
            int c = (cgrp*4 + ct)*16 + lm;
            #pragma unroll
            for (int r = 0; r < 4; r++) {
                int nl = nc*32 + rowg*16 + lq*4 + r;
                partial[((long)(nb0+nl)*KSPLIT_ + kz)*PSTR_ + c] = acc[nc][ct][r];
            }
        }
    }
}

// ---------------- fused: r1 streaming reduce + r2/r3 LSE + final projection ----------------
__global__ void r23out_kernel(const float* __restrict__ partial, const void* __restrict__ b_rel,
                              const float* __restrict__ mu, const float* __restrict__ c23,
                              const int* __restrict__ hts, const int* __restrict__ mention_idx,
                              const float* __restrict__ W_bilF, const void* __restrict__ b_bil,
                              void* __restrict__ out, const int* __restrict__ dtf) {
    int bp = blockIdx.x;
    int b = bp >> 8;
    int c = threadIdx.x;
    int isbf = dtf[0];
    __shared__ float row[292];
    if (c < C_) {
        const float* pr = partial + (long)bp*KSPLIT_*PSTR_;
        float r1v = 0.f;
        #pragma unroll 8
        for (int kz = 0; kz < KSPLIT_; kz++)
            r1v += pr[kz*PSTR_ + c];
        r1v += ldIn(b_rel, c, isbf);
        int h_e = hts[bp*2+0], t_e = hts[bp*2+1];
        const float* mu2h = mu;
        const float* mu2t = mu + 32768;
        const float* mu3h = mu + 65536;
        const float* mu3t = mu + 98304;
        float ah2[4], at2[4], ah3[4], at3[4];
        for (int m = 0; m < 4; m++) {
            int emh = mention_idx[(b*E_ + h_e)*M_ + m];
            int emt = mention_idx[(b*E_ + t_e)*M_ + m];
            ah2[m] = mu2h[(long)(b*128 + emh)*128 + c];
            ah3[m] = mu3h[(long)(b*128 + emh)*128 + c];
            at2[m] = mu2t[(long)(b*128 + emt)*128 + c];
            at3[m] = mu3t[(long)(b*128 + emt)*128 + c];
        }
        float c2 = c23[c], c3 = c23[C_ + c];
        float v2[16], v3[16];
        int q = 0;
        for (int i = 0; i < 4; i++) {
            for (int j = 0; j < 4; j++, q++) {
                float x2 = ah2[i] + at2[j] + c2;
                v2[q] = tanhf(x2);
                float x3 = ah3[i] + at3[j] + c3;
                float t = tanhf(0.7978845608028654f * (x3 + 0.044715f*x3*x3*x3));
                v3[q] = 0.5f * x3 * (1.0f + t);
            }
        }
        float m2 = v2[0], m3 = v3[0];
        for (q = 1; q < 16; q++) { m2 = fmaxf(m2, v2[q]); m3 = fmaxf(m3, v3[q]); }
        float s2 = 0.f, s3 = 0.f;
        for (q = 0; q < 16; q++) { s2 += expf(v2[q]-m2); s3 += expf(v3[q]-m3); }
        row[c]        = r1v;
        row[C_ + c]   = m2 + logf(s2);
        row[2*C_ + c] = m3 + logf(s3);
    }
    __syncthreads();
    if (c >= C_) return;
    float a0 = 0.f, a1 = 0.f, a2 = 0.f, a3 = 0.f;
    #pragma unroll 4
    for (int k = 0; k < 288; k += 4) {
        a0 += row[k+0] * W_bilF[(k+0)*C_ + c];
        a1 += row[k+1] * W_bilF[(k+1)*C_ + c];
        a2 += row[k+2] * W_bilF[(k+2)*C_ + c];
        a3 += row[k+3] * W_bilF[(k+3)*C_ + c];
    }
    a0 += row[288] * W_bilF[288*C_ + c];
    a1 += row[289] * W_bilF[289*C_ + c];
    a2 += row[290] * W_bilF[290*C_ + c];
    float v = a0 + a1 + a2 + a3 + ldIn(b_bil, c, isbf);
    if (isbf) ((bf16*)out)[(long)bp*C_ + c] = (bf16)v;
    else      ((float*)out)[(long)bp*C_ + c] = v;
}

extern "C" void kernel_launch(void* const* d_in, const int* in_sizes, int n_in,
                              void* d_out, int out_size, void* d_ws, size_t ws_size,
                              hipStream_t stream) {
    const void* seq        = d_in[0];
    const void* attn       = d_in[1];
    const int*  entity_pos = (const int*)d_in[2];
    const int*  hts        = (const int*)d_in[3];
    const int*  mention_idx= (const int*)d_in[4];
    const void* W_head     = d_in[5];
    const void* b_head     = d_in[6];
    const void* W_tail     = d_in[7];
    const void* b_tail     = d_in[8];
    const void* W_rel      = d_in[9];
    const void* b_rel      = d_in[10];
    const void* W_fh       = d_in[11];
    const void* W_ft       = d_in[12];
    const void* b_f        = d_in[13];
    const void* W_unet     = d_in[14];
    const void* b_unet     = d_in[15];
    const void* W_mlp      = d_in[16];
    const void* b_mlp      = d_in[17];
    const void* W_bil      = d_in[18];
    const void* b_bil      = d_in[19];

    float* w = (float*)d_ws;
    int*   dtf      = (int*)w;                               // 64
    unsigned short* mentb = (unsigned short*)(w + 64);       // 98304 fl
    float* ent_emb  = w + 98368;                             // 49152
    float* ent_att  = w + 147520;                            // 393216
    unsigned short* htb = (unsigned short*)(w + 540736);     // 131072 fl
    float* rs       = w + 671808;                            // 393216
    float* hz       = w + 1065024;                           // 393216
    float* tz       = w + 1458240;                           // 393216
    float* mu       = w + 1851456;                           // 131072
    float* c23      = w + 1982528;                           // 256
    unsigned short* seqT  = (unsigned short*)(w + 1982784);  // 393216 fl
    unsigned short* WhT   = (unsigned short*)(w + 2376000);  // 589824 fl
    unsigned short* WtT   = (unsigned short*)(w + 2965824);  // 589824 fl
    unsigned short* WfhT  = (unsigned short*)(w + 3555648);  // 294912 fl
    unsigned short* WftT  = (unsigned short*)(w + 3850560);  // 294912 fl
    unsigned short* WunetT= (unsigned short*)(w + 4145472);  // 49152 fl
    unsigned short* WmlpT = (unsigned short*)(w + 4194624);  // 49152 fl
    unsigned short* Tbh   = (unsigned short*)(w + 4243776);  // 98304 fl
    unsigned short* Tbt   = (unsigned short*)(w + 4342080);  // 98304 fl
    unsigned short* hcatb = (unsigned short*)(w + 4440384);  // 393216 fl
    unsigned short* tcatb = (unsigned short*)(w + 4833600);  // 393216 fl
    unsigned short* WBt   = (unsigned short*)(w + 5226816);  // 2752512 fl (tiled: 768*7168 ushorts, exact fit)
    float* partial  = w + 7979328;                           // 3670016 fl (used: 512*48*128 = 3145728)
    float* W_bilF   = w + 11649344;                          // 28227 fl

    // 0. dtype detection + c23 init
    dtype_detect<<<1, 256, 0, stream>>>(seq, dtf, c23);
    // 1. prep: transposes + W_bilF + c23 + W_rel conv
    {
        PrepArgs a = {};
        const void* srcs[8] = {W_head, W_tail, W_fh, W_ft, W_unet, W_mlp, seq, seq};
        long offs[8]   = {0,0,0,0,0,0,0,393216};
        int Ks[8]      = {1536,1536,768,768,768,768,512,512};
        int Ncols8[8]  = {768,768,768,768,97,97,768,768};
        int Npads[8]   = {768,768,768,768,128,128,768,768};
        unsigned short* dsts[8] = {WhT, WtT, WfhT, WftT, WunetT, WmlpT, seqT, seqT+393216};
        for (int z = 0; z < 8; z++) {
            a.src[z]=srcs[z]; a.off[z]=offs[z]; a.K[z]=Ks[z];
            a.Ncols[z]=Ncols8[z]; a.Npad[z]=Npads[z]; a.dst[z]=dsts[z];
        }
        a.W_bil = W_bil; a.W_bilF = W_bilF;
        a.b_f = b_f; a.W_unet = W_unet; a.b_unet = b_unet;
        a.W_mlp = W_mlp; a.b_mlp = b_mlp; a.c23 = c23;
        a.W_rel = W_rel; a.WBt = WBt;
        prep_kernel<<<dim3(48, 16, 11), 256, 0, stream>>>(a, dtf);
    }
    // 2. gather: entatt + ment
    gather_kernel<<<768 + 64, 256, 0, stream>>>(seq, attn, entity_pos, mentb, ent_emb, ent_att, dtf);
    // 3. ht attention (normalized, bf16)
    htatt_kernel<<<N_, 256, 0, stream>>>(ent_att, hts, htb);
    // 4. gemmA: rs (z=0,1) + T_{h,t} (z=2,3)  [32x32 tiles]
    {
        MfmaJob ga = {};
        for (int z = 0; z < 2; z++) {
            ga.A[z] = htb + (long)z*256*512; ga.Bt[z] = seqT + (long)z*393216;
            ga.bias[z] = nullptr; ga.C[z] = rs + (long)z*256*768;
            ga.K[z] = 512; ga.ldc[z] = 768; ga.act[z] = 0; ga.obf[z] = 0;
        }
        ga.A[2] = mentb; ga.Bt[2] = WfhT; ga.bias[2] = nullptr; ga.C[2] = Tbh;
        ga.K[2] = 768; ga.ldc[2] = 768; ga.act[2] = 0; ga.obf[2] = 1;
        ga.A[3] = mentb; ga.Bt[3] = WftT; ga.bias[3] = nullptr; ga.C[3] = Tbt;
        ga.K[3] = 768; ga.ldc[3] = 768; ga.act[3] = 0; ga.obf[3] = 1;
        mfma_nt2_kernel<<<dim3(8, 24, 4), 256, 0, stream>>>(ga, dtf);
    }
    // 5. concatenated inputs (bf16)
    catb_kernel<<<N_, 256, 0, stream>>>(ent_emb, rs, hts, hcatb, tcatb);
    // 6. gemmB: hz/tz = tanh(cat @ W + b)
    {
        MfmaJob ga = {};
        ga.A[0] = hcatb; ga.Bt[0] = WhT; ga.bias[0] = b_head; ga.C[0] = hz;
        ga.A[1] = tcatb; ga.Bt[1] = WtT; ga.bias[1] = b_tail; ga.C[1] = tz;
        for (int z = 0; z < 2; z++) { ga.K[z] = 1536; ga.ldc[z] = 768; ga.act[z] = 1; ga.obf[z] = 0; }
        mfma_nt2_kernel<<<dim3(16, 24, 2), 256, 0, stream>>>(ga, dtf);
    }
    // 7. gemmC: mu_q = T @ W_{unet,mlp}
    {
        MfmaJob ga = {};
        const unsigned short* As[4] = {Tbh, Tbt, Tbh, Tbt};
        const unsigned short* Bs[4] = {WunetT, WunetT, WmlpT, WmlpT};
        for (int q = 0; q < 4; q++) {
            ga.A[q] = As[q]; ga.Bt[q] = Bs[q]; ga.bias[q] = nullptr;
            ga.C[q] = mu + q*32768;
            ga.K[q] = 768; ga.ldc[q] = 128; ga.act[q] = 0; ga.obf[q] = 0;
        }
        mfma_nt2_kernel<<<dim3(8, 4, 4), 256, 0, stream>>>(ga, dtf);
    }
    // 8. r1 partials via MFMA (deep-compute blocks: 128 n-rows x 1024 k each)
    r1_mfma_kernel<<<dim3(KSPLIT_, 4), 256, 0, stream>>>(hz, tz, WBt, partial);
    // 9. fused reduce + r2/r3 + final projection
    r23out_kernel<<<N_, 128, 0, stream>>>(partial, b_rel, mu, c23, hts, mention_idx,
                                          W_bilF, b_bil, d_out, dtf);
}

// Round 7
// 242.827 us; speedup vs baseline: 1.1264x; 1.0657x over previous
//
#include <hip/hip_runtime.h>
#include <hip/hip_bf16.h>

// Problem constants
#define B_  2
#define L_  512
#define D_  768
#define H_  12
#define E_  32
#define M_  4
#define P_  256
#define EMB_ 768
#define BS_ 64
#define C_  97
#define N_  (B_*P_)   // 512

#define KTOT_    49152      // EMB*BS
#define CPAD_    112        // 97 padded to 7*16
#define KSPLIT_  48
#define KCHUNK_  (KTOT_/KSPLIT_)   // 1024, 16 ks-steps of 64; divides 4096 -> no group crossing
#define PSTR_    128        // partial chunk stride (floats): 512 B, cache-line exclusive
#define TILE_    (CPAD_*64) // 7168 ushorts = 14336 B per k-step tile of WBt

typedef __hip_bfloat16 bf16;
typedef __attribute__((ext_vector_type(8))) short bf16x8;
typedef __attribute__((ext_vector_type(4))) float f32x4;
typedef __attribute__((ext_vector_type(8))) float f32x8;

__device__ inline float ldIn(const void* p, long idx, int isbf) {
    return isbf ? (float)((const bf16*)p)[idx] : ((const float*)p)[idx];
}

__device__ inline unsigned short f2bf(float f) {
    bf16 h = (bf16)f;
    return *(unsigned short*)&h;
}

__device__ inline float bf2f(unsigned short u) {
    bf16 h = *(bf16*)&u;
    return (float)h;
}

// ---------------- K0: dtype detection + c23 zero-init ----------------
__global__ void dtype_detect(const void* __restrict__ seq, int* __restrict__ flag,
                             float* __restrict__ c23) {
    __shared__ int cnt;
    if (threadIdx.x == 0) cnt = 0;
    if (threadIdx.x < 2*C_) c23[threadIdx.x] = 0.f;
    __syncthreads();
    const unsigned short* u = (const unsigned short*)seq;
    int bad = 0;
    for (int i = threadIdx.x; i < 1024; i += 256) {
        unsigned short e = (u[i] >> 7) & 0xFF;
        if (e >= 140) bad++;
    }
    atomicAdd(&cnt, bad);
    __syncthreads();
    if (threadIdx.x == 0) flag[0] = (cnt < 16) ? 1 : 0;   // 1 = bf16 inputs
}

// ---------------- prep (z-reordered): z=0 c23 (96 blocks), z=1 W_rel conv,
// z=2..9 transposes, z=10 W_bil->f32. The old z=9 c23 ran on 8 blocks x 96
// serial latency-bound iters -> few-CU tail; now 96 blocks x 8 iters and it
// dispatches FIRST. W_rel (biggest slice, 30 MB) dispatches second.
struct PrepArgs {
    const void* src[8];
    long off[8];
    int K[8];
    int Ncols[8];
    int Npad[8];
    unsigned short* dst[8];
    const void* W_bil;  float* W_bilF;
    const void* b_f; const void* W_unet; const void* b_unet;
    const void* W_mlp; const void* b_mlp; float* c23;
    const void* W_rel; unsigned short* WBt;
};

union PrepSm {
    float T[32][65];                 // 8320 B
    unsigned short TW[CPAD_][72];    // 16128 B
};

__global__ void prep_kernel(PrepArgs a, const int* __restrict__ dtf) {
    int isbf = dtf[0];
    int z = blockIdx.z;
    __shared__ PrepSm sm;
    int tid = threadIdx.x;
    if (z == 0) {
        // c23 partial: 96 blocks x 8 d-rows, coalesced over c, atomic accumulate
        int lin = blockIdx.y*48 + blockIdx.x;
        if (lin >= 96) return;
        int c = tid;
        if (c >= C_) return;
        float s2 = 0.f, s3 = 0.f;
        int d0 = lin*8;
        for (int i = 0; i < 8; i++) {
            int d = d0 + i;
            float bf = ldIn(a.b_f, d, isbf);
            s2 += bf * ldIn(a.W_unet, (long)d*C_ + c, isbf);
            s3 += bf * ldIn(a.W_mlp,  (long)d*C_ + c, isbf);
        }
        if (lin == 0) {
            s2 += ldIn(a.b_unet, c, isbf);
            s3 += ldIn(a.b_mlp,  c, isbf);
        }
        atomicAdd(&a.c23[c], s2);
        atomicAdd(&a.c23[C_ + c], s3);
    } else if (z == 1) {
        // W_rel -> WBt TILED: [kstep][c][64] bf16, c padded to 112.
        int lin = blockIdx.y*48 + blockIdx.x;
        if (lin >= KTOT_/64) return;
        int k0 = lin * 64;
        for (int idx = tid; idx < 64*97; idx += 256) {
            int kk = idx / 97, c = idx % 97;
            sm.TW[c][kk] = f2bf(ldIn(a.W_rel, (long)(k0+kk)*C_ + c, isbf));
        }
        for (int idx = tid; idx < 15*64; idx += 256) {
            sm.TW[97 + (idx>>6)][idx & 63] = 0;
        }
        __syncthreads();
        unsigned short* tb = a.WBt + (long)lin*TILE_;
        for (int t = 0; t < 4; t++) {
            int idx = tid + t*256;      // < 896 = 112*8
            if (idx < 896) {
                int c = idx >> 3, kc = idx & 7;
                *(uint4*)(tb + idx*8) = *(uint4*)&sm.TW[c][kc*8];
            }
        }
    } else if (z <= 9) {
        int j = z - 2;
        int K = a.K[j], Ncols = a.Ncols[j], Npad = a.Npad[j];
        int k0 = blockIdx.x*32, n0 = blockIdx.y*64;
        if (k0 >= K || n0 >= Npad) return;
        const void* src = a.src[j];
        long off = a.off[j];
        unsigned short* dst = a.dst[j];
        // read: 64 consecutive cols per row (coalesced 128/256 B)
        int c64 = tid & 63, r4 = tid >> 6;
        for (int p = 0; p < 8; p++) {
            int r = r4 + p*4;
            int n = n0 + c64;
            sm.T[r][c64] = (n < Ncols) ? ldIn(src, off + (long)(k0+r)*Ncols + n, isbf) : 0.f;
        }
        __syncthreads();
        // write: 32 consecutive k per n (coalesced)
        int cc = tid & 31, n8 = tid >> 5;
        for (int p = 0; p < 8; p++) {
            int nn = n8 + p*8;
            dst[(long)(n0+nn)*K + k0 + cc] = f2bf(sm.T[cc][nn]);
        }
    } else {
        int lin = blockIdx.y*48 + blockIdx.x;
        int idx = lin*256 + tid;
        if (idx < 291*C_) a.W_bilF[idx] = ldIn(a.W_bil, idx, isbf);
    }
}

// ---------------- gather: bx<768 entatt, else ment ----------------
__global__ void gather_kernel(const void* __restrict__ seq, const void* __restrict__ attn,
                              const int* __restrict__ entity_pos,
                              unsigned short* __restrict__ mentb, float* __restrict__ ent_emb,
                              float* __restrict__ ent_att, const int* __restrict__ dtf) {
    int isbf = dtf[0];
    if (blockIdx.x < 768) {
        int beh = blockIdx.x;
        int h = beh % H_;
        int be = beh / H_;
        int b = be >> 5;
        int pos[M_];
        for (int m = 0; m < M_; m++) pos[m] = entity_pos[be*M_+m] + 1;
        for (int l = threadIdx.x; l < L_; l += 256) {
            float s = 0.f;
            for (int m = 0; m < M_; m++)
                s += ldIn(attn, (((long)(b*H_ + h))*L_ + pos[m])*L_ + l, isbf);
            ent_att[(long)beh*L_ + l] = 0.25f * s;
        }
    } else {
        int be = blockIdx.x - 768;     // 0..63
        int b = be >> 5;
        int pos[M_];
        for (int m = 0; m < M_; m++) pos[m] = entity_pos[be*M_+m] + 1;
        for (int d = threadIdx.x; d < D_; d += 256) {
            float x[M_];
            for (int m = 0; m < M_; m++) {
                x[m] = ldIn(seq, ((long)b*L_ + pos[m])*D_ + d, isbf);
                mentb[((long)be*M_ + m)*D_ + d] = f2bf(x[m]);
            }
            float mx = fmaxf(fmaxf(x[0],x[1]), fmaxf(x[2],x[3]));
            float s = expf(x[0]-mx)+expf(x[1]-mx)+expf(x[2]-mx)+expf(x[3]-mx);
            ent_emb[(long)be*D_ + d] = mx + logf(s);
        }
    }
}

// ---------------- K3: ht_att (bf16) = normalize_L( mean_H(ha*ta) ) ----------------
__global__ void htatt_kernel(const float* __restrict__ ent_att, const int* __restrict__ hts,
                             unsigned short* __restrict__ htb) {
    int bp = blockIdx.x;            // 512 blocks
    int b = bp >> 8;
    int h_e = hts[bp*2+0], t_e = hts[bp*2+1];
    const float* ea_h = ent_att + (long)((b*E_ + h_e)*H_)*L_;
    const float* ea_t = ent_att + (long)((b*E_ + t_e)*H_)*L_;
    __shared__ float red[256];
    float v[2];
    for (int t = 0; t < 2; t++) {
        int l = threadIdx.x + t*256;
        float s = 0.f;
        for (int h = 0; h < H_; h++) s += ea_h[h*L_+l] * ea_t[h*L_+l];
        v[t] = s * (1.0f/H_);
    }
    red[threadIdx.x] = v[0] + v[1];
    __syncthreads();
    for (int off = 128; off > 0; off >>= 1) {
        if (threadIdx.x < off) red[threadIdx.x] += red[threadIdx.x+off];
        __syncthreads();
    }
    float inv = 1.0f / (red[0] + 1e-5f);
    for (int t = 0; t < 2; t++) {
        int l = threadIdx.x + t*256;
        htb[(long)bp*L_ + l] = f2bf(v[t] * inv);
    }
}

// ---------------- catb: hcatb=[hs,rs], tcatb=[ts,rs] in bf16 ----------------
__global__ void catb_kernel(const float* __restrict__ ent_emb, const float* __restrict__ rs,
                            const int* __restrict__ hts,
                            unsigned short* __restrict__ hcatb, unsigned short* __restrict__ tcatb) {
    int n = blockIdx.x;             // 512
    int b = n >> 8;
    int h_e = hts[n*2+0], t_e = hts[n*2+1];
    const float* eh = ent_emb + (long)(b*E_ + h_e)*D_;
    const float* et = ent_emb + (long)(b*E_ + t_e)*D_;
    const float* r  = rs + (long)n*D_;
    for (int k = threadIdx.x; k < D_; k += 256) {
        hcatb[(long)n*1536 + k] = f2bf(eh[k]);
        tcatb[(long)n*1536 + k] = f2bf(et[k]);
        unsigned short rb = f2bf(r[k]);
        hcatb[(long)n*1536 + 768 + k] = rb;
        tcatb[(long)n*1536 + 768 + k] = rb;
    }
}

// ---------------- Generic MFMA GEMM (double-buffered), 32x32 tiles ----------------
struct MfmaJob {
    const unsigned short* A[4];
    const unsigned short* Bt[4];
    const void* bias[4];
    void* C[4];
    int K[4];
    int ldc[4];
    int act[4];
    int obf[4];
};

__global__ void mfma_nt2_kernel(MfmaJob args, const int* __restrict__ dtf) {
    int z = blockIdx.z;
    const unsigned short* A  = args.A[z];
    const unsigned short* Bt = args.Bt[z];
    const void* bias = args.bias[z];
    void* C = args.C[z];
    int K = args.K[z], ldc = args.ldc[z], act = args.act[z], obf = args.obf[z];
    __shared__ unsigned short Al[2][32][72];
    __shared__ unsigned short Btl[2][32][72];
    int m0 = blockIdx.x*32, n0 = blockIdx.y*32;
    int tid = threadIdx.x, wave = tid>>6, lane = tid&63;
    int lm = lane&15, lq = lane>>4;
    int rowg = wave>>1, cgrp = wave&1;   // wave -> (row half, col half)
    int rr = tid >> 3;                // 0..31
    int kc = (tid & 7) * 8;           // col offset in ushorts
    uint4 ra, rb;

    ra = *(const uint4*)(A  + (long)(m0+rr)*K + kc);
    rb = *(const uint4*)(Bt + (long)(n0+rr)*K + kc);
    *(uint4*)&Al[0][rr][kc]  = ra;
    *(uint4*)&Btl[0][rr][kc] = rb;

    int nst = K >> 6;
    f32x4 acc = {};
    for (int ks = 0; ks < nst; ks++) {
        __syncthreads();
        if (ks+1 < nst) {
            int k0 = (ks+1) << 6;
            ra = *(const uint4*)(A  + (long)(m0+rr)*K + k0 + kc);
            rb = *(const uint4*)(Bt + (long)(n0+rr)*K + k0 + kc);
        }
        int cb = ks & 1;
        #pragma unroll
        for (int half = 0; half < 2; half++) {
            bf16x8 af  = *(bf16x8*)&Al[cb][rowg*16+lm][half*32+lq*8];
            bf16x8 bfr = *(bf16x8*)&Btl[cb][cgrp*16+lm][half*32+lq*8];
            acc = __builtin_amdgcn_mfma_f32_16x16x32_bf16(af, bfr, acc, 0, 0, 0);
        }
        if (ks+1 < nst) {
            int nb = (ks+1) & 1;
            *(uint4*)&Al[nb][rr][kc]  = ra;
            *(uint4*)&Btl[nb][rr][kc] = rb;
        }
    }
    int isbf = dtf[0];
    int n = n0 + cgrp*16 + lm;
    float bia = bias ? ldIn(bias, n, isbf) : 0.f;
    #pragma unroll
    for (int r = 0; r < 4; r++) {
        int m = m0 + rowg*16 + lq*4 + r;
        float v = acc[r] + bia;
        if (act == 1) v = tanhf(v);
        if (obf) ((unsigned short*)C)[(long)m*ldc + n] = f2bf(v);
        else     ((float*)C)[(long)m*ldc + n] = v;
    }
}

// ================= r1 via MFMA =================
// v6: occupancy + amortization jointly. 512-thread blocks (8 waves), 64 n-rows
// each, grid (48,8)=384 -> every CU active, up to 2 blocks/CU (LDS 36.6 KB),
// 4 waves/SIMD VGPR cap via __launch_bounds__(512,4). v5's 192-block config
// left 64 CUs idle and 1 wave/SIMD elsewhere (Occupancy 6.7%) -> all latency
// exposed. Wave mapping: wave = (row-group 0..3) x (c-half 0..1).
// WBt tiled [kstep][c][64]; double-buffered staging; partial layout unchanged.
__global__ __launch_bounds__(512, 4)
void r1_mfma_kernel(const float* __restrict__ hz, const float* __restrict__ tz,
                    const unsigned short* __restrict__ WBt,
                    float* __restrict__ partial) {
    __shared__ unsigned short Btl[2][CPAD_][72];   // 32256 B
    __shared__ float hzL[64][17];                  // 4352 B
    int kz = blockIdx.x;
    int nb0 = blockIdx.y * 64;
    int gk0 = kz * (KCHUNK_/64);     // global k-step base = kz*16
    int gi0 = kz * 16;               // hz col base
    int g0 = (kz * KCHUNK_) >> 12;   // tz group, fixed for the whole chunk
    int tid = threadIdx.x;
    int wave = tid >> 6, lane = tid & 63;
    int lm = lane & 15, lq = lane >> 4;
    int rowg = wave >> 1;            // 0..3  (16-row group)
    int cgrp = wave & 1;             // 0 -> c-tiles 0..3, 1 -> c-tiles 4..6
    int nct = 4 - cgrp;
    int nrow = nb0 + rowg*16 + lm;

    // hz tile 64 rows x 16 cols -> LDS (1024 floats, 1 float2 per thread)
    {
        int r = tid >> 3, q = (tid & 7) * 2;
        float2 v = *(const float2*)(hz + (long)(nb0 + r)*EMB_ + gi0 + q);
        hzL[r][q] = v.x; hzL[r][q+1] = v.y;
    }
    // tz fragment for this lane's row, f32 in registers (16 VGPR)
    f32x8 t0, t1;
    {
        const float* tp = tz + (long)nrow*EMB_ + g0*64;
        float4 x0 = *(const float4*)(tp + lq*8);
        float4 y0 = *(const float4*)(tp + lq*8 + 4);
        float4 x1 = *(const float4*)(tp + 32 + lq*8);
        float4 y1 = *(const float4*)(tp + 32 + lq*8 + 4);
        t0[0]=x0.x; t0[1]=x0.y; t0[2]=x0.z; t0[3]=x0.w;
        t0[4]=y0.x; t0[5]=y0.y; t0[6]=y0.z; t0[7]=y0.w;
        t1[0]=x1.x; t1[1]=x1.y; t1[2]=x1.z; t1[3]=x1.w;
        t1[4]=y1.x; t1[5]=y1.y; t1[6]=y1.z; t1[7]=y1.w;
    }

    // prologue: stage W tile for ks=0 (contiguous 14336 B; 896 uint4 / 512 thr)
    {
        const unsigned short* tbp = WBt + (long)gk0*TILE_;
        #pragma unroll
        for (int t = 0; t < 2; t++) {
            int idx = tid + t*512;
            if (idx < 896) {
                *(uint4*)&Btl[0][idx>>3][(idx&7)*8] = *(const uint4*)(tbp + idx*8);
            }
        }
    }

    f32x4 acc[4] = {};
    uint4 rb[2];
    #pragma unroll 2
    for (int ks = 0; ks < KCHUNK_/64; ks++) {
        __syncthreads();
        if (ks+1 < KCHUNK_/64) {
            const unsigned short* tbp = WBt + (long)(gk0+ks+1)*TILE_;
            #pragma unroll
            for (int t = 0; t < 2; t++) {
                int idx = tid + t*512;
                if (idx < 896) {
                    rb[t] = *(const uint4*)(tbp + idx*8);
                }
            }
        }
        int cb = ks & 1;
        // B-frags for this wave's c-tiles, both halves: read once per tile
        bf16x8 bf0[4], bf1[4];
        #pragma unroll
        for (int ct = 0; ct < 4; ct++) {
            if (ct < nct) {
                bf0[ct] = *(bf16x8*)&Btl[cb][(cgrp*4+ct)*16 + lm][lq*8];
                bf1[ct] = *(bf16x8*)&Btl[cb][(cgrp*4+ct)*16 + lm][32 + lq*8];
            }
        }
        float hvk = hzL[rowg*16 + lm][ks];
        unsigned short oa0[8], oa1[8];
        #pragma unroll
        for (int e = 0; e < 8; e++) {
            oa0[e] = f2bf(t0[e] * hvk);
            oa1[e] = f2bf(t1[e] * hvk);
        }
        bf16x8 a0 = *(bf16x8*)oa0;
        bf16x8 a1 = *(bf16x8*)oa1;
        #pragma unroll
        for (int ct = 0; ct < 4; ct++) {
            if (ct < nct) {
                acc[ct] = __builtin_amdgcn_mfma_f32_16x16x32_bf16(a0, bf0[ct], acc[ct], 0, 0, 0);
                acc[ct] = __builtin_amdgcn_mfma_f32_16x16x32_bf16(a1, bf1[ct], acc[ct], 0, 0, 0);
            }
        }
        if (ks+1 < KCHUNK_/64) {
            int nb = (ks+1) & 1;
            #pragma unroll
            for (int t = 0; t < 2; t++) {
                int idx = tid + t*512;
                if (idx < 896) {
                    *(uint4*)&Btl[nb][idx>>3][(idx&7)*8] = rb[t];
                }
            }
        }
    }
    // epilogue: write ALL 4 c-tiles per wave (c 0..127) so every 512-B chunk
    // is fully written -> no partial-sector RMW. acc[3] of cgrp=1 is zero.
    #pragma unroll
    for (int ct = 0; ct < 4; ct++) {
        int c = (cgrp*4 + ct)*16 + lm;
        #pragma unroll
        for (int r = 0; r < 4; r++) {
            int nl = rowg*16 + lq*4 + r;
            partial[((long)(nb0+nl)*KSPLIT_ + kz)*PSTR_ + c] = acc[ct][r];
        }
    }
}

// ---------------- fused: r1 streaming reduce + r2/r3 LSE + final projection ----------------
__global__ void r23out_kernel(const float* __restrict__ partial, const void* __restrict__ b_rel,
                              const float* __restrict__ mu, const float* __restrict__ c23,
                              const int* __restrict__ hts, const int* __restrict__ mention_idx,
                              const float* __restrict__ W_bilF, const void* __restrict__ b_bil,
                              void* __restrict__ out, const int* __restrict__ dtf) {
    int bp = blockIdx.x;
    int b = bp >> 8;
    int c = threadIdx.x;
    int isbf = dtf[0];
    __shared__ float row[292];
    if (c < C_) {
        const float* pr = partial + (long)bp*KSPLIT_*PSTR_;
        float r1v = 0.f;
        #pragma unroll 8
        for (int kz = 0; kz < KSPLIT_; kz++)
            r1v += pr[kz*PSTR_ + c];
        r1v += ldIn(b_rel, c, isbf);
        int h_e = hts[bp*2+0], t_e = hts[bp*2+1];
        const float* mu2h = mu;
        const float* mu2t = mu + 32768;
        const float* mu3h = mu + 65536;
        const float* mu3t = mu + 98304;
        float ah2[4], at2[4], ah3[4], at3[4];
        for (int m = 0; m < 4; m++) {
            int emh = mention_idx[(b*E_ + h_e)*M_ + m];
            int emt = mention_idx[(b*E_ + t_e)*M_ + m];
            ah2[m] = mu2h[(long)(b*128 + emh)*128 + c];
            ah3[m] = mu3h[(long)(b*128 + emh)*128 + c];
            at2[m] = mu2t[(long)(b*128 + emt)*128 + c];
            at3[m] = mu3t[(long)(b*128 + emt)*128 + c];
        }
        float c2 = c23[c], c3 = c23[C_ + c];
        float v2[16], v3[16];
        int q = 0;
        for (int i = 0; i < 4; i++) {
            for (int j = 0; j < 4; j++, q++) {
                float x2 = ah2[i] + at2[j] + c2;
                v2[q] = tanhf(x2);
                float x3 = ah3[i] + at3[j] + c3;
                float t = tanhf(0.7978845608028654f * (x3 + 0.044715f*x3*x3*x3));
                v3[q] = 0.5f * x3 * (1.0f + t);
            }
        }
        float m2 = v2[0], m3 = v3[0];
        for (q = 1; q < 16; q++) { m2 = fmaxf(m2, v2[q]); m3 = fmaxf(m3, v3[q]); }
        float s2 = 0.f, s3 = 0.f;
        for (q = 0; q < 16; q++) { s2 += expf(v2[q]-m2); s3 += expf(v3[q]-m3); }
        row[c]        = r1v;
        row[C_ + c]   = m2 + logf(s2);
        row[2*C_ + c] = m3 + logf(s3);
    }
    __syncthreads();
    if (c >= C_) return;
    float a0 = 0.f, a1 = 0.f, a2 = 0.f, a3 = 0.f;
    #pragma unroll 4
    for (int k = 0; k < 288; k += 4) {
        a0 += row[k+0] * W_bilF[(k+0)*C_ + c];
        a1 += row[k+1] * W_bilF[(k+1)*C_ + c];
        a2 += row[k+2] * W_bilF[(k+2)*C_ + c];
        a3 += row[k+3] * W_bilF[(k+3)*C_ + c];
    }
    a0 += row[288] * W_bilF[288*C_ + c];
    a1 += row[289] * W_bilF[289*C_ + c];
    a2 += row[290] * W_bilF[290*C_ + c];
    float v = a0 + a1 + a2 + a3 + ldIn(b_bil, c, isbf);
    if (isbf) ((bf16*)out)[(long)bp*C_ + c] = (bf16)v;
    else      ((float*)out)[(long)bp*C_ + c] = v;
}

extern "C" void kernel_launch(void* const* d_in, const int* in_sizes, int n_in,
                              void* d_out, int out_size, void* d_ws, size_t ws_size,
                              hipStream_t stream) {
    const void* seq        = d_in[0];
    const void* attn       = d_in[1];
    const int*  entity_pos = (const int*)d_in[2];
    const int*  hts        = (const int*)d_in[3];
    const int*  mention_idx= (const int*)d_in[4];
    const void* W_head     = d_in[5];
    const void* b_head     = d_in[6];
    const void* W_tail     = d_in[7];
    const void* b_tail     = d_in[8];
    const void* W_rel      = d_in[9];
    const void* b_rel      = d_in[10];
    const void* W_fh       = d_in[11];
    const void* W_ft       = d_in[12];
    const void* b_f        = d_in[13];
    const void* W_unet     = d_in[14];
    const void* b_unet     = d_in[15];
    const void* W_mlp      = d_in[16];
    const void* b_mlp      = d_in[17];
    const void* W_bil      = d_in[18];
    const void* b_bil      = d_in[19];

    float* w = (float*)d_ws;
    int*   dtf      = (int*)w;                               // 64
    unsigned short* mentb = (unsigned short*)(w + 64);       // 98304 fl
    float* ent_emb  = w + 98368;                             // 49152
    float* ent_att  = w + 147520;                            // 393216
    unsigned short* htb = (unsigned short*)(w + 540736);     // 131072 fl
    float* rs       = w + 671808;                            // 393216
    float* hz       = w + 1065024;                           // 393216
    float* tz       = w + 1458240;                           // 393216
    float* mu       = w + 1851456;                           // 131072
    float* c23      = w + 1982528;                           // 256
    unsigned short* seqT  = (unsigned short*)(w + 1982784);  // 393216 fl
    unsigned short* WhT   = (unsigned short*)(w + 2376000);  // 589824 fl
    unsigned short* WtT   = (unsigned short*)(w + 2965824);  // 589824 fl
    unsigned short* WfhT  = (unsigned short*)(w + 3555648);  // 294912 fl
    unsigned short* WftT  = (unsigned short*)(w + 3850560);  // 294912 fl
    unsigned short* WunetT= (unsigned short*)(w + 4145472);  // 49152 fl
    unsigned short* WmlpT = (unsigned short*)(w + 4194624);  // 49152 fl
    unsigned short* Tbh   = (unsigned short*)(w + 4243776);  // 98304 fl
    unsigned short* Tbt   = (unsigned short*)(w + 4342080);  // 98304 fl
    unsigned short* hcatb = (unsigned short*)(w + 4440384);  // 393216 fl
    unsigned short* tcatb = (unsigned short*)(w + 4833600);  // 393216 fl
    unsigned short* WBt   = (unsigned short*)(w + 5226816);  // 2752512 fl (tiled: 768*7168 ushorts, exact fit)
    float* partial  = w + 7979328;                           // 3670016 fl (used: 512*48*128 = 3145728)
    float* W_bilF   = w + 11649344;                          // 28227 fl

    // 0. dtype detection + c23 init
    dtype_detect<<<1, 256, 0, stream>>>(seq, dtf, c23);
    // 1. prep: c23 (z=0) + W_rel conv (z=1) + transposes (z=2..9) + W_bilF (z=10)
    {
        PrepArgs a = {};
        const void* srcs[8] = {W_head, W_tail, W_fh, W_ft, W_unet, W_mlp, seq, seq};
        long offs[8]   = {0,0,0,0,0,0,0,393216};
        int Ks[8]      = {1536,1536,768,768,768,768,512,512};
        int Ncols8[8]  = {768,768,768,768,97,97,768,768};
        int Npads[8]   = {768,768,768,768,128,128,768,768};
        unsigned short* dsts[8] = {WhT, WtT, WfhT, WftT, WunetT, WmlpT, seqT, seqT+393216};
        for (int z = 0; z < 8; z++) {
            a.src[z]=srcs[z]; a.off[z]=offs[z]; a.K[z]=Ks[z];
            a.Ncols[z]=Ncols8[z]; a.Npad[z]=Npads[z]; a.dst[z]=dsts[z];
        }
        a.W_bil = W_bil; a.W_bilF = W_bilF;
        a.b_f = b_f; a.W_unet = W_unet; a.b_unet = b_unet;
        a.W_mlp = W_mlp; a.b_mlp = b_mlp; a.c23 = c23;
        a.W_rel = W_rel; a.WBt = WBt;
        prep_kernel<<<dim3(48, 16, 11), 256, 0, stream>>>(a, dtf);
    }
    // 2. gather: entatt + ment
    gather_kernel<<<768 + 64, 256, 0, stream>>>(seq, attn, entity_pos, mentb, ent_emb, ent_att, dtf);
    // 3. ht attention (normalized, bf16)
    htatt_kernel<<<N_, 256, 0, stream>>>(ent_att, hts, htb);
    // 4. gemmA: rs (z=0,1) + T_{h,t} (z=2,3)  [32x32 tiles]
    {
        MfmaJob ga = {};
        for (int z = 0; z < 2; z++) {
            ga.A[z] = htb + (long)z*256*512; ga.Bt[z] = seqT + (long)z*393216;
            ga.bias[z] = nullptr; ga.C[z] = rs + (long)z*256*768;
            ga.K[z] = 512; ga.ldc[z] = 768; ga.act[z] = 0; ga.obf[z] = 0;
        }
        ga.A[2] = mentb; ga.Bt[2] = WfhT; ga.bias[2] = nullptr; ga.C[2] = Tbh;
        ga.K[2] = 768; ga.ldc[2] = 768; ga.act[2] = 0; ga.obf[2] = 1;
        ga.A[3] = mentb; ga.Bt[3] = WftT; ga.bias[3] = nullptr; ga.C[3] = Tbt;
        ga.K[3] = 768; ga.ldc[3] = 768; ga.act[3] = 0; ga.obf[3] = 1;
        mfma_nt2_kernel<<<dim3(8, 24, 4), 256, 0, stream>>>(ga, dtf);
    }
    // 5. concatenated inputs (bf16)
    catb_kernel<<<N_, 256, 0, stream>>>(ent_emb, rs, hts, hcatb, tcatb);
    // 6. gemmB: hz/tz = tanh(cat @ W + b)
    {
        MfmaJob ga = {};
        ga.A[0] = hcatb; ga.Bt[0] = WhT; ga.bias[0] = b_head; ga.C[0] = hz;
        ga.A[1] = tcatb; ga.Bt[1] = WtT; ga.bias[1] = b_tail; ga.C[1] = tz;
        for (int z = 0; z < 2; z++) { ga.K[z] = 1536; ga.ldc[z] = 768; ga.act[z] = 1; ga.obf[z] = 0; }
        mfma_nt2_kernel<<<dim3(16, 24, 2), 256, 0, stream>>>(ga, dtf);
    }
    // 7. gemmC: mu_q = T @ W_{unet,mlp}
    {
        MfmaJob ga = {};
        const unsigned short* As[4] = {Tbh, Tbt, Tbh, Tbt};
        const unsigned short* Bs[4] = {WunetT, WunetT, WmlpT, WmlpT};
        for (int q = 0; q < 4; q++) {
            ga.A[q] = As[q]; ga.Bt[q] = Bs[q]; ga.bias[q] = nullptr;
            ga.C[q] = mu + q*32768;
            ga.K[q] = 768; ga.ldc[q] = 128; ga.act[q] = 0; ga.obf[q] = 0;
        }
        mfma_nt2_kernel<<<dim3(8, 4, 4), 256, 0, stream>>>(ga, dtf);
    }
    // 8. r1 partials via MFMA (512-thr blocks, 64 n-rows, grid 48x8 = 384)
    r1_mfma_kernel<<<dim3(KSPLIT_, 8), 512, 0, stream>>>(hz, tz, WBt, partial);
    // 9. fused reduce + r2/r3 + final projection
    r23out_kernel<<<N_, 128, 0, stream>>>(partial, b_rel, mu, c23, hts, mention_idx,
                                          W_bilF, b_bil, d_out, dtf);
}